// Round 13
// baseline (579.464 us; speedup 1.0000x reference)
//
#include <hip/hip_runtime.h>

#define NN 163842
#define NE 983040
#define NB 641   // ceil(NN/256)

// ---------------- degree count (int) ----------------
__global__ __launch_bounds__(256) void deg_count(const int* __restrict__ dst,
                                                 int* __restrict__ degi, int E) {
    int e = blockIdx.x * 256 + threadIdx.x;
    if (e < E) atomicAdd(&degi[dst[e]], 1);
}

// ---------------- exclusive scan of degi -> cursor ----------------
__global__ __launch_bounds__(256) void scan1(const int* __restrict__ degi,
                                             int* __restrict__ cursor,
                                             int* __restrict__ bsum, int n) {
    __shared__ int tmp[256];
    int t = threadIdx.x;
    int i = blockIdx.x * 256 + t;
    int v = (i < n) ? degi[i] : 0;
    tmp[t] = v;
    __syncthreads();
    for (int o = 1; o < 256; o <<= 1) {
        int x = (t >= o) ? tmp[t - o] : 0;
        __syncthreads();
        tmp[t] += x;
        __syncthreads();
    }
    if (i < n) cursor[i] = tmp[t] - v;            // exclusive
    if (t == 255) bsum[blockIdx.x] = tmp[255];    // block total
}

__global__ void scan2(int* __restrict__ bsum, int nb) {
    __shared__ int tmp[1024];
    int t = threadIdx.x;
    int v = (t < nb) ? bsum[t] : 0;
    tmp[t] = v;
    __syncthreads();
    for (int o = 1; o < 1024; o <<= 1) {
        int x = (t >= o) ? tmp[t - o] : 0;
        __syncthreads();
        tmp[t] += x;
        __syncthreads();
    }
    if (t < nb) bsum[t] = tmp[t] - v;
}

__global__ __launch_bounds__(256) void scan3(int* __restrict__ cursor,
                                             const int* __restrict__ bsum, int n) {
    int i = blockIdx.x * 256 + threadIdx.x;
    if (i < n) cursor[i] += bsum[blockIdx.x];
}

// ---------------- scatter: permute edges into dst-sorted order ----------------
// edat[p] = {src (bits), ea.x, ea.y, 0} — one 16-B record per edge
__global__ __launch_bounds__(256) void scatter_k(const int* __restrict__ src,
                                                 const int* __restrict__ dst,
                                                 const float* __restrict__ ea,
                                                 int* __restrict__ cursor,
                                                 float4* __restrict__ edat, int E) {
    int e = blockIdx.x * 256 + threadIdx.x;
    if (e >= E) return;
    int p = atomicAdd(&cursor[dst[e]], 1);
    edat[p] = make_float4(__int_as_float(src[e]), ea[2 * e], ea[2 * e + 1], 0.0f);
}

// ---------------- pad x [N,22] -> xp [N,32] ----------------
__global__ __launch_bounds__(256) void pad_x(const float* __restrict__ x,
                                             float* __restrict__ xp, int n) {
    int t = blockIdx.x * 256 + threadIdx.x;
    if (t >= n * 32) return;
    int r = t >> 5, c = t & 31;
    xp[t] = (c < 22) ? x[r * 22 + c] : 0.0f;
}

static __device__ __forceinline__ void fma4(float4& a, float g, const float4& hv) {
    a.x = fmaf(g, hv.x, a.x);
    a.y = fmaf(g, hv.y, a.y);
    a.z = fmaf(g, hv.z, a.z);
    a.w = fmaf(g, hv.w, a.w);
}

// ---------------- fused gaussian + dst-centric aggregation (no atomics) ----------------
// S[d, 3*CINP] = [S0|S1|S2],  S_k[c] = (1/deg) * sum_e exp(..)_k * h[src_e*hs + c]
template <int CINP>
__global__ __launch_bounds__(256) void aggregate_g(const float* __restrict__ h, int hs,
                                                   const float4* __restrict__ edat,
                                                   const float* __restrict__ mu,
                                                   const float* __restrict__ sigma,
                                                   const int* __restrict__ cursor,
                                                   const int* __restrict__ degi,
                                                   float* __restrict__ S, int n) {
    float m0x = mu[0], m0y = mu[1], m1x = mu[2], m1y = mu[3], m2x = mu[4], m2y = mu[5];
    float i0x = 1.0f / (1e-15f + sigma[0] * sigma[0]);
    float i0y = 1.0f / (1e-15f + sigma[1] * sigma[1]);
    float i1x = 1.0f / (1e-15f + sigma[2] * sigma[2]);
    float i1y = 1.0f / (1e-15f + sigma[3] * sigma[3]);
    float i2x = 1.0f / (1e-15f + sigma[4] * sigma[4]);
    float i2y = 1.0f / (1e-15f + sigma[5] * sigma[5]);
    constexpr int LPN = CINP / 4;                     // lanes per node
    const int c4 = (threadIdx.x % LPN) * 4;
    const int sw = (blockIdx.x * 256 + threadIdx.x) / LPN;
    const int nsw = gridDim.x * (256 / LPN);
    for (int d = sw; d < n; d += nsw) {
        int end = cursor[d];
        int dg  = degi[d];
        int p   = end - dg;
        float4 a0 = {0, 0, 0, 0}, a1 = {0, 0, 0, 0}, a2 = {0, 0, 0, 0};
        for (; p + 4 <= end; p += 4) {
            float4 ed[4], hv[4];
#pragma unroll
            for (int u = 0; u < 4; ++u) ed[u] = edat[p + u];
#pragma unroll
            for (int u = 0; u < 4; ++u)
                hv[u] = *(const float4*)(h + (long)__float_as_int(ed[u].x) * hs + c4);
#pragma unroll
            for (int u = 0; u < 4; ++u) {
                float dx, dy;
                dx = ed[u].y - m0x; dy = ed[u].z - m0y;
                float g0 = __expf(-0.5f * (dx * dx * i0x + dy * dy * i0y));
                dx = ed[u].y - m1x; dy = ed[u].z - m1y;
                float g1 = __expf(-0.5f * (dx * dx * i1x + dy * dy * i1y));
                dx = ed[u].y - m2x; dy = ed[u].z - m2y;
                float g2 = __expf(-0.5f * (dx * dx * i2x + dy * dy * i2y));
                fma4(a0, g0, hv[u]);
                fma4(a1, g1, hv[u]);
                fma4(a2, g2, hv[u]);
            }
        }
        for (; p < end; ++p) {
            float4 ed = edat[p];
            float4 hv = *(const float4*)(h + (long)__float_as_int(ed.x) * hs + c4);
            float dx, dy;
            dx = ed.y - m0x; dy = ed.z - m0y;
            float g0 = __expf(-0.5f * (dx * dx * i0x + dy * dy * i0y));
            dx = ed.y - m1x; dy = ed.z - m1y;
            float g1 = __expf(-0.5f * (dx * dx * i1x + dy * dy * i1y));
            dx = ed.y - m2x; dy = ed.z - m2y;
            float g2 = __expf(-0.5f * (dx * dx * i2x + dy * dy * i2y));
            fma4(a0, g0, hv);
            fma4(a1, g1, hv);
            fma4(a2, g2, hv);
        }
        float inv = 1.0f / (float)max(dg, 1);
        float* Sr = S + (long)d * (3 * CINP);
        a0.x *= inv; a0.y *= inv; a0.z *= inv; a0.w *= inv;
        a1.x *= inv; a1.y *= inv; a1.z *= inv; a1.w *= inv;
        a2.x *= inv; a2.y *= inv; a2.z *= inv; a2.w *= inv;
        *(float4*)(Sr + c4)            = a0;
        *(float4*)(Sr + CINP + c4)     = a1;
        *(float4*)(Sr + 2 * CINP + c4) = a2;
    }
}

// ---------------- build Wc[4*CINP, 64] = [g0;g1;g2;root], zero-padded ----------------
template <int CIN, int CINP, int COUTR>
__global__ __launch_bounds__(256) void build_wc(const float* __restrict__ g,
                                                const float* __restrict__ root,
                                                float* __restrict__ Wc) {
    int t = blockIdx.x * 256 + threadIdx.x;
    constexpr int KTOT = 4 * CINP;
    if (t >= KTOT * 64) return;
    int kt = t >> 6, o = t & 63;
    int k = kt / CINP, c = kt % CINP;
    float v = 0.0f;
    if (c < CIN && o < COUTR)
        v = (k < 3) ? g[c * (3 * COUTR) + k * COUTR + o] : root[c * COUTR + o];
    Wc[t] = v;
}

// ---------------- row GEMM, software-pipelined K-chunked LDS: relu([A|h]@Wc + b) ----
// Block = 64 rows. Chunks of 96 floats staged via REGISTER prefetch: global loads for
// chunk ch+1 issued before computing chunk ch, so barriers only fence LDS writes.
// amdgpu_waves_per_eu(1,4): the allocator's default targets MAX occupancy (~8 waves/EU
// -> 40-VGPR cap) and spilled pf[] to scratch in rounds 11-12 (197 MB WRITE);
// __launch_bounds__' 2nd arg only raises the MIN. Capping the target range at 4
// waves/EU gives a 128-VGPR budget; occupancy stays LDS-bound (25.6 KB -> 6 blk/CU).
// NOTE: out must NOT alias h (multiple waves read the full h row per output row).
template <int KA, int KH, int CW>
__global__ __attribute__((amdgpu_waves_per_eu(1, 4))) __launch_bounds__(256)
void rowgemm_p(const float* __restrict__ A,
               const float* __restrict__ h, int hs,
               const float* __restrict__ Wc,
               const float* __restrict__ bias,
               int coutr, float* __restrict__ out, int n) {
    constexpr int KA4 = KA / 4;
    constexpr int KH4 = KH / 4;
    constexpr int C4  = 24;                      // float4 per chunk (96 floats)
    constexpr int NCH = KA4 / C4;                // A chunks (KA4 % 24 == 0)
    constexpr int HI  = KH4 / 4;                 // prefetch regs used for h chunk
    __shared__ float4 sa[64 * 25];               // odd stride 25: conflict-free b128
    const int row0 = blockIdx.x * 64;
    const int lane = threadIdx.x & 63;           // local row
    const int wid  = __builtin_amdgcn_readfirstlane(threadIdx.x >> 6);
    const int cb   = wid * CW;                   // column strip base
    const int row  = row0 + lane;
    const bool valid = (row < n) && (cb < coutr);
    float acc[CW];
#pragma unroll
    for (int c = 0; c < CW; ++c) acc[c] = 0.0f;

    float4 pf[6];
    // prefetch A chunk 0 (64*24/256 = 6 float4/thread, coalesced)
#pragma unroll
    for (int i = 0; i < 6; ++i) {
        int f = threadIdx.x + i * 256;
        int r = f / C4, c4 = f - r * C4;
        int gr = row0 + r; if (gr > n - 1) gr = n - 1;
        pf[i] = ((const float4*)(A + (long)gr * KA))[c4];
    }
#pragma unroll
    for (int ch = 0; ch < NCH; ++ch) {
        __syncthreads();                          // prev compute done
#pragma unroll
        for (int i = 0; i < 6; ++i) {
            int f = threadIdx.x + i * 256;
            int r = f / C4, c4 = f - r * C4;
            sa[r * 25 + c4] = pf[i];
        }
        __syncthreads();
        // prefetch next chunk into registers (loads in flight during compute)
        if (ch + 1 < NCH) {
#pragma unroll
            for (int i = 0; i < 6; ++i) {
                int f = threadIdx.x + i * 256;
                int r = f / C4, c4 = f - r * C4;
                int gr = row0 + r; if (gr > n - 1) gr = n - 1;
                pf[i] = ((const float4*)(A + (long)gr * KA))[(ch + 1) * C4 + c4];
            }
        } else {
#pragma unroll
            for (int i = 0; i < HI; ++i) {
                int f = threadIdx.x + i * 256;
                int r = f / KH4, c4 = f - r * KH4;
                int gr = row0 + r; if (gr > n - 1) gr = n - 1;
                pf[i] = ((const float4*)(h + (long)gr * hs))[c4];
            }
        }
#pragma unroll 2
        for (int k4 = 0; k4 < C4; ++k4) {
            float4 a = sa[lane * 25 + k4];
            float av[4] = {a.x, a.y, a.z, a.w};
#pragma unroll
            for (int j = 0; j < 4; ++j) {
                const float* wrow = Wc + ((ch * C4 + k4) * 4 + j) * 64 + cb;  // s_load
#pragma unroll
                for (int c = 0; c < CW; ++c)
                    acc[c] = fmaf(av[j], wrow[c], acc[c]);
            }
        }
    }
    // h chunk
    __syncthreads();
#pragma unroll
    for (int i = 0; i < HI; ++i) {
        int f = threadIdx.x + i * 256;
        int r = f / KH4, c4 = f - r * KH4;
        sa[r * 25 + c4] = pf[i];
    }
    __syncthreads();
#pragma unroll 2
    for (int k4 = 0; k4 < KH4; ++k4) {
        float4 a = sa[lane * 25 + k4];
        float av[4] = {a.x, a.y, a.z, a.w};
#pragma unroll
        for (int j = 0; j < 4; ++j) {
            const float* wrow = Wc + ((KA4 + k4) * 4 + j) * 64 + cb;
#pragma unroll
            for (int c = 0; c < CW; ++c)
                acc[c] = fmaf(av[j], wrow[c], acc[c]);
        }
    }
    if (valid) {
        const float* bh = bias + cb;
        float4* o4 = (float4*)(out + (long)row * coutr + cb);
#pragma unroll
        for (int c4 = 0; c4 < CW / 4; ++c4) {
            float4 v;
            v.x = fmaxf(acc[4 * c4 + 0] + bh[4 * c4 + 0], 0.0f);
            v.y = fmaxf(acc[4 * c4 + 1] + bh[4 * c4 + 1], 0.0f);
            v.z = fmaxf(acc[4 * c4 + 2] + bh[4 * c4 + 2], 0.0f);
            v.w = fmaxf(acc[4 * c4 + 3] + bh[4 * c4 + 3], 0.0f);
            o4[c4] = v;
        }
    }
}

// ---------------- final FC (64->2) + log_softmax ----------------
__global__ __launch_bounds__(256) void final_kernel(const float* __restrict__ h,
                                                    const float* __restrict__ fcw,
                                                    const float* __restrict__ fcb,
                                                    float* __restrict__ out, int n) {
    int i = blockIdx.x * 256 + threadIdx.x;
    if (i >= n) return;
    const float4* h4 = (const float4*)(h + (long)i * 64);
    float l0 = fcb[0];
    float l1 = fcb[1];
#pragma unroll
    for (int j4 = 0; j4 < 16; ++j4) {
        float4 hv = h4[j4];
        l0 = fmaf(hv.x, fcw[8 * j4 + 0], l0);
        l1 = fmaf(hv.x, fcw[8 * j4 + 1], l1);
        l0 = fmaf(hv.y, fcw[8 * j4 + 2], l0);
        l1 = fmaf(hv.y, fcw[8 * j4 + 3], l1);
        l0 = fmaf(hv.z, fcw[8 * j4 + 4], l0);
        l1 = fmaf(hv.z, fcw[8 * j4 + 5], l1);
        l0 = fmaf(hv.w, fcw[8 * j4 + 6], l0);
        l1 = fmaf(hv.w, fcw[8 * j4 + 7], l1);
    }
    float mx  = fmaxf(l0, l1);
    float lse = mx + logf(__expf(l0 - mx) + __expf(l1 - mx));
    out[2 * (long)i]     = l0 - lse;
    out[2 * (long)i + 1] = l1 - lse;
}

extern "C" void kernel_launch(void* const* d_in, const int* in_sizes, int n_in,
                              void* d_out, int out_size, void* d_ws, size_t ws_size,
                              hipStream_t stream) {
    const float* x   = (const float*)d_in[0];
    const int*   ei  = (const int*)d_in[1];
    const float* ea  = (const float*)d_in[2];
    const float* g_[3]  = {(const float*)d_in[3],  (const float*)d_in[8],  (const float*)d_in[13]};
    const float* mu_[3] = {(const float*)d_in[4],  (const float*)d_in[9],  (const float*)d_in[14]};
    const float* sg_[3] = {(const float*)d_in[5],  (const float*)d_in[10], (const float*)d_in[15]};
    const float* rt_[3] = {(const float*)d_in[6],  (const float*)d_in[11], (const float*)d_in[16]};
    const float* bs_[3] = {(const float*)d_in[7],  (const float*)d_in[12], (const float*)d_in[17]};
    const float* fcw = (const float*)d_in[18];
    const float* fcb = (const float*)d_in[19];
    float* out = (float*)d_out;
    (void)in_sizes; (void)n_in; (void)out_size; (void)ws_size;

    // workspace carve-up (~230 MB)
    char* w = (char*)d_ws;
    size_t off = 0;
    auto carve = [&](size_t bytes) -> void* {
        void* p = (void*)(w + off);
        off += (bytes + 255) & ~(size_t)255;
        return p;
    };
    int*    degi   = (int*)carve((size_t)NN * 4);
    int*    cursor = (int*)carve((size_t)NN * 4);
    float4* edat   = (float4*)carve((size_t)NE * 16);
    float*  S      = (float*)carve((size_t)NN * 192 * 4);   // A buffer, max 3*CINP=192
    int*    bsum   = (int*)carve(1024 * 4);
    float*  Wc     = (float*)carve((size_t)256 * 64 * 4);
    float*  xp     = (float*)carve((size_t)NN * 32 * 4);    // padded input [N,32]
    float*  hA     = (float*)carve((size_t)NN * 32 * 4);    // layer-0 out [N,32]
    float*  hB     = (float*)carve((size_t)NN * 64 * 4);    // layer-1 out [N,64]
    // xp/hA are adjacent 256-aligned carves (each a multiple of 256 B) forming a
    // contiguous [N,64] region that is dead after layer 1 -> reuse as layer-2 out.
    float*  hC     = xp;

    const int* src = ei;
    const int* dst = ei + NE;
    const int EB = (NE + 255) / 256;
    const int GB = (NN + 63) / 64;   // 2561 blocks: 64 rows per block

    // ---- CSR build (once per call) ----
    hipMemsetAsync(degi, 0, (size_t)NN * 4, stream);
    deg_count<<<EB, 256, 0, stream>>>(dst, degi, NE);
    scan1<<<NB, 256, 0, stream>>>(degi, cursor, bsum, NN);
    scan2<<<1, 1024, 0, stream>>>(bsum, NB);
    scan3<<<NB, 256, 0, stream>>>(cursor, bsum, NN);
    scatter_k<<<EB, 256, 0, stream>>>(src, dst, ea, cursor, edat, NE);
    pad_x<<<(NN * 32 + 255) / 256, 256, 0, stream>>>(x, xp, NN);

    // ---- layer 0: 22(pad32) -> 32  (A = [N,96], CW=8: no wasted FMAs) ----
    aggregate_g<32><<<1024, 256, 0, stream>>>(xp, 32, edat, mu_[0], sg_[0], cursor, degi, S, NN);
    build_wc<22, 32, 32><<<32, 256, 0, stream>>>(g_[0], rt_[0], Wc);
    rowgemm_p<96, 32, 8><<<GB, 256, 0, stream>>>(S, xp, 32, Wc, bs_[0], 32, hA, NN);

    // ---- layer 1: 32 -> 64  (A = [N,96]) ----
    aggregate_g<32><<<1024, 256, 0, stream>>>(hA, 32, edat, mu_[1], sg_[1], cursor, degi, S, NN);
    build_wc<32, 32, 64><<<32, 256, 0, stream>>>(g_[1], rt_[1], Wc);
    rowgemm_p<96, 32, 16><<<GB, 256, 0, stream>>>(S, hA, 32, Wc, bs_[1], 64, hB, NN);

    // ---- layer 2: 64 -> 64  (A = [N,192]; out -> hC, distinct from h=hB) ----
    aggregate_g<64><<<2048, 256, 0, stream>>>(hB, 64, edat, mu_[2], sg_[2], cursor, degi, S, NN);
    build_wc<64, 64, 64><<<64, 256, 0, stream>>>(g_[2], rt_[2], Wc);
    rowgemm_p<192, 64, 16><<<GB, 256, 0, stream>>>(S, hB, 64, Wc, bs_[2], 64, hC, NN);

    final_kernel<<<(NN + 255) / 256, 256, 0, stream>>>(hC, fcw, fcb, out, NN);
}

// Round 14
// 515.097 us; speedup vs baseline: 1.1250x; 1.1250x over previous
//
#include <hip/hip_runtime.h>

#define NN 163842
#define NE 983040
#define NB 641   // ceil(NN/256)

// ---------------- degree count (int) ----------------
__global__ __launch_bounds__(256) void deg_count(const int* __restrict__ dst,
                                                 int* __restrict__ degi, int E) {
    int e = blockIdx.x * 256 + threadIdx.x;
    if (e < E) atomicAdd(&degi[dst[e]], 1);
}

// ---------------- exclusive scan of degi -> cursor ----------------
__global__ __launch_bounds__(256) void scan1(const int* __restrict__ degi,
                                             int* __restrict__ cursor,
                                             int* __restrict__ bsum, int n) {
    __shared__ int tmp[256];
    int t = threadIdx.x;
    int i = blockIdx.x * 256 + t;
    int v = (i < n) ? degi[i] : 0;
    tmp[t] = v;
    __syncthreads();
    for (int o = 1; o < 256; o <<= 1) {
        int x = (t >= o) ? tmp[t - o] : 0;
        __syncthreads();
        tmp[t] += x;
        __syncthreads();
    }
    if (i < n) cursor[i] = tmp[t] - v;            // exclusive
    if (t == 255) bsum[blockIdx.x] = tmp[255];    // block total
}

__global__ void scan2(int* __restrict__ bsum, int nb) {
    __shared__ int tmp[1024];
    int t = threadIdx.x;
    int v = (t < nb) ? bsum[t] : 0;
    tmp[t] = v;
    __syncthreads();
    for (int o = 1; o < 1024; o <<= 1) {
        int x = (t >= o) ? tmp[t - o] : 0;
        __syncthreads();
        tmp[t] += x;
        __syncthreads();
    }
    if (t < nb) bsum[t] = tmp[t] - v;
}

__global__ __launch_bounds__(256) void scan3(int* __restrict__ cursor,
                                             const int* __restrict__ bsum, int n) {
    int i = blockIdx.x * 256 + threadIdx.x;
    if (i < n) cursor[i] += bsum[blockIdx.x];
}

// ---------------- scatter: permute edges into dst-sorted order ----------------
// edat[p] = {src (bits), ea.x, ea.y, 0} — one 16-B record per edge
__global__ __launch_bounds__(256) void scatter_k(const int* __restrict__ src,
                                                 const int* __restrict__ dst,
                                                 const float* __restrict__ ea,
                                                 int* __restrict__ cursor,
                                                 float4* __restrict__ edat, int E) {
    int e = blockIdx.x * 256 + threadIdx.x;
    if (e >= E) return;
    int p = atomicAdd(&cursor[dst[e]], 1);
    edat[p] = make_float4(__int_as_float(src[e]), ea[2 * e], ea[2 * e + 1], 0.0f);
}

// ---------------- pad x [N,22] -> xp [N,32] ----------------
__global__ __launch_bounds__(256) void pad_x(const float* __restrict__ x,
                                             float* __restrict__ xp, int n) {
    int t = blockIdx.x * 256 + threadIdx.x;
    if (t >= n * 32) return;
    int r = t >> 5, c = t & 31;
    xp[t] = (c < 22) ? x[r * 22 + c] : 0.0f;
}

static __device__ __forceinline__ void fma4(float4& a, float g, const float4& hv) {
    a.x = fmaf(g, hv.x, a.x);
    a.y = fmaf(g, hv.y, a.y);
    a.z = fmaf(g, hv.z, a.z);
    a.w = fmaf(g, hv.w, a.w);
}

// ---------------- fused gaussian + dst-centric aggregation (no atomics) ----------------
// S[d, 3*CINP] = [S0|S1|S2],  S_k[c] = (1/deg) * sum_e exp(..)_k * h[src_e*hs + c]
template <int CINP>
__global__ __launch_bounds__(256) void aggregate_g(const float* __restrict__ h, int hs,
                                                   const float4* __restrict__ edat,
                                                   const float* __restrict__ mu,
                                                   const float* __restrict__ sigma,
                                                   const int* __restrict__ cursor,
                                                   const int* __restrict__ degi,
                                                   float* __restrict__ S, int n) {
    float m0x = mu[0], m0y = mu[1], m1x = mu[2], m1y = mu[3], m2x = mu[4], m2y = mu[5];
    float i0x = 1.0f / (1e-15f + sigma[0] * sigma[0]);
    float i0y = 1.0f / (1e-15f + sigma[1] * sigma[1]);
    float i1x = 1.0f / (1e-15f + sigma[2] * sigma[2]);
    float i1y = 1.0f / (1e-15f + sigma[3] * sigma[3]);
    float i2x = 1.0f / (1e-15f + sigma[4] * sigma[4]);
    float i2y = 1.0f / (1e-15f + sigma[5] * sigma[5]);
    constexpr int LPN = CINP / 4;                     // lanes per node
    const int c4 = (threadIdx.x % LPN) * 4;
    const int sw = (blockIdx.x * 256 + threadIdx.x) / LPN;
    const int nsw = gridDim.x * (256 / LPN);
    for (int d = sw; d < n; d += nsw) {
        int end = cursor[d];
        int dg  = degi[d];
        int p   = end - dg;
        float4 a0 = {0, 0, 0, 0}, a1 = {0, 0, 0, 0}, a2 = {0, 0, 0, 0};
        for (; p + 4 <= end; p += 4) {
            float4 ed[4], hv[4];
#pragma unroll
            for (int u = 0; u < 4; ++u) ed[u] = edat[p + u];
#pragma unroll
            for (int u = 0; u < 4; ++u)
                hv[u] = *(const float4*)(h + (long)__float_as_int(ed[u].x) * hs + c4);
#pragma unroll
            for (int u = 0; u < 4; ++u) {
                float dx, dy;
                dx = ed[u].y - m0x; dy = ed[u].z - m0y;
                float g0 = __expf(-0.5f * (dx * dx * i0x + dy * dy * i0y));
                dx = ed[u].y - m1x; dy = ed[u].z - m1y;
                float g1 = __expf(-0.5f * (dx * dx * i1x + dy * dy * i1y));
                dx = ed[u].y - m2x; dy = ed[u].z - m2y;
                float g2 = __expf(-0.5f * (dx * dx * i2x + dy * dy * i2y));
                fma4(a0, g0, hv[u]);
                fma4(a1, g1, hv[u]);
                fma4(a2, g2, hv[u]);
            }
        }
        for (; p < end; ++p) {
            float4 ed = edat[p];
            float4 hv = *(const float4*)(h + (long)__float_as_int(ed.x) * hs + c4);
            float dx, dy;
            dx = ed.y - m0x; dy = ed.z - m0y;
            float g0 = __expf(-0.5f * (dx * dx * i0x + dy * dy * i0y));
            dx = ed.y - m1x; dy = ed.z - m1y;
            float g1 = __expf(-0.5f * (dx * dx * i1x + dy * dy * i1y));
            dx = ed.y - m2x; dy = ed.z - m2y;
            float g2 = __expf(-0.5f * (dx * dx * i2x + dy * dy * i2y));
            fma4(a0, g0, hv);
            fma4(a1, g1, hv);
            fma4(a2, g2, hv);
        }
        float inv = 1.0f / (float)max(dg, 1);
        float* Sr = S + (long)d * (3 * CINP);
        a0.x *= inv; a0.y *= inv; a0.z *= inv; a0.w *= inv;
        a1.x *= inv; a1.y *= inv; a1.z *= inv; a1.w *= inv;
        a2.x *= inv; a2.y *= inv; a2.z *= inv; a2.w *= inv;
        *(float4*)(Sr + c4)            = a0;
        *(float4*)(Sr + CINP + c4)     = a1;
        *(float4*)(Sr + 2 * CINP + c4) = a2;
    }
}

// ---------------- build Wc[4*CINP, 64] = [g0;g1;g2;root], zero-padded ----------------
template <int CIN, int CINP, int COUTR>
__global__ __launch_bounds__(256) void build_wc(const float* __restrict__ g,
                                                const float* __restrict__ root,
                                                float* __restrict__ Wc) {
    int t = blockIdx.x * 256 + threadIdx.x;
    constexpr int KTOT = 4 * CINP;
    if (t >= KTOT * 64) return;
    int kt = t >> 6, o = t & 63;
    int k = kt / CINP, c = kt % CINP;
    float v = 0.0f;
    if (c < CIN && o < COUTR)
        v = (k < 3) ? g[c * (3 * COUTR) + k * COUTR + o] : root[c * COUTR + o];
    Wc[t] = v;
}

// ---------------- row GEMM, K-chunked LDS staging (round-10 proven): relu([A|h]@Wc+b) -
// Block = 64 rows. K in chunks of 96 floats staged into a 64x25-float4 LDS tile
// (25.6 KB -> 6 blocks/CU); lane=row, wave=CW-col strip, acc[CW] in regs across
// barriers. W rows wave-uniform -> s_load broadcast. No register prefetch: the
// pipelined variant (rounds 11-13) ALWAYS spilled pf[] to scratch (150-190 MB WRITE)
// regardless of launch_bounds / waves_per_eu — keep live state minimal instead.
// NOTE: out must NOT alias h (multiple waves read the full h row per output row).
template <int KA, int KH, int CW>
__global__ __launch_bounds__(256) void rowgemm_c(const float* __restrict__ A,
                                                 const float* __restrict__ h, int hs,
                                                 const float* __restrict__ Wc,
                                                 const float* __restrict__ bias,
                                                 int coutr, float* __restrict__ out, int n) {
    constexpr int KA4 = KA / 4;
    constexpr int KH4 = KH / 4;
    constexpr int C4  = 24;                      // float4 per chunk (96 floats)
    constexpr int NCH = KA4 / C4;                // A chunks (KA4 % 24 == 0)
    __shared__ float4 sa[64 * 25];               // odd stride 25: conflict-free b128
    const int row0 = blockIdx.x * 64;
    const int lane = threadIdx.x & 63;           // local row
    const int wid  = __builtin_amdgcn_readfirstlane(threadIdx.x >> 6);
    const int cb   = wid * CW;                   // column strip base
    const int row  = row0 + lane;
    const bool valid = (row < n) && (cb < coutr);
    float acc[CW];
#pragma unroll
    for (int c = 0; c < CW; ++c) acc[c] = 0.0f;

#pragma unroll
    for (int ch = 0; ch < NCH; ++ch) {
        __syncthreads();
        for (int f = threadIdx.x; f < 64 * C4; f += 256) {
            int r = f / C4, c4 = f - (f / C4) * C4;
            int gr = row0 + r; if (gr > n - 1) gr = n - 1;
            sa[r * 25 + c4] = ((const float4*)(A + (long)gr * KA))[ch * C4 + c4];
        }
        __syncthreads();
#pragma unroll 2
        for (int k4 = 0; k4 < C4; ++k4) {
            float4 a = sa[lane * 25 + k4];
            float av[4] = {a.x, a.y, a.z, a.w};
#pragma unroll
            for (int j = 0; j < 4; ++j) {
                const float* wrow = Wc + ((ch * C4 + k4) * 4 + j) * 64 + cb;  // s_load
#pragma unroll
                for (int c = 0; c < CW; ++c)
                    acc[c] = fmaf(av[j], wrow[c], acc[c]);
            }
        }
    }
    // h chunk (KH4 <= 24)
    __syncthreads();
    for (int f = threadIdx.x; f < 64 * KH4; f += 256) {
        int r = f / KH4, c4 = f - (f / KH4) * KH4;
        int gr = row0 + r; if (gr > n - 1) gr = n - 1;
        sa[r * 25 + c4] = ((const float4*)(h + (long)gr * hs))[c4];
    }
    __syncthreads();
#pragma unroll 2
    for (int k4 = 0; k4 < KH4; ++k4) {
        float4 a = sa[lane * 25 + k4];
        float av[4] = {a.x, a.y, a.z, a.w};
#pragma unroll
        for (int j = 0; j < 4; ++j) {
            const float* wrow = Wc + ((KA4 + k4) * 4 + j) * 64 + cb;
#pragma unroll
            for (int c = 0; c < CW; ++c)
                acc[c] = fmaf(av[j], wrow[c], acc[c]);
        }
    }
    if (valid) {
        const float* bh = bias + cb;
        float4* o4 = (float4*)(out + (long)row * coutr + cb);
#pragma unroll
        for (int c4 = 0; c4 < CW / 4; ++c4) {
            float4 v;
            v.x = fmaxf(acc[4 * c4 + 0] + bh[4 * c4 + 0], 0.0f);
            v.y = fmaxf(acc[4 * c4 + 1] + bh[4 * c4 + 1], 0.0f);
            v.z = fmaxf(acc[4 * c4 + 2] + bh[4 * c4 + 2], 0.0f);
            v.w = fmaxf(acc[4 * c4 + 3] + bh[4 * c4 + 3], 0.0f);
            o4[c4] = v;
        }
    }
}

// ---------------- final FC (64->2) + log_softmax ----------------
__global__ __launch_bounds__(256) void final_kernel(const float* __restrict__ h,
                                                    const float* __restrict__ fcw,
                                                    const float* __restrict__ fcb,
                                                    float* __restrict__ out, int n) {
    int i = blockIdx.x * 256 + threadIdx.x;
    if (i >= n) return;
    const float4* h4 = (const float4*)(h + (long)i * 64);
    float l0 = fcb[0];
    float l1 = fcb[1];
#pragma unroll
    for (int j4 = 0; j4 < 16; ++j4) {
        float4 hv = h4[j4];
        l0 = fmaf(hv.x, fcw[8 * j4 + 0], l0);
        l1 = fmaf(hv.x, fcw[8 * j4 + 1], l1);
        l0 = fmaf(hv.y, fcw[8 * j4 + 2], l0);
        l1 = fmaf(hv.y, fcw[8 * j4 + 3], l1);
        l0 = fmaf(hv.z, fcw[8 * j4 + 4], l0);
        l1 = fmaf(hv.z, fcw[8 * j4 + 5], l1);
        l0 = fmaf(hv.w, fcw[8 * j4 + 6], l0);
        l1 = fmaf(hv.w, fcw[8 * j4 + 7], l1);
    }
    float mx  = fmaxf(l0, l1);
    float lse = mx + logf(__expf(l0 - mx) + __expf(l1 - mx));
    out[2 * (long)i]     = l0 - lse;
    out[2 * (long)i + 1] = l1 - lse;
}

extern "C" void kernel_launch(void* const* d_in, const int* in_sizes, int n_in,
                              void* d_out, int out_size, void* d_ws, size_t ws_size,
                              hipStream_t stream) {
    const float* x   = (const float*)d_in[0];
    const int*   ei  = (const int*)d_in[1];
    const float* ea  = (const float*)d_in[2];
    const float* g_[3]  = {(const float*)d_in[3],  (const float*)d_in[8],  (const float*)d_in[13]};
    const float* mu_[3] = {(const float*)d_in[4],  (const float*)d_in[9],  (const float*)d_in[14]};
    const float* sg_[3] = {(const float*)d_in[5],  (const float*)d_in[10], (const float*)d_in[15]};
    const float* rt_[3] = {(const float*)d_in[6],  (const float*)d_in[11], (const float*)d_in[16]};
    const float* bs_[3] = {(const float*)d_in[7],  (const float*)d_in[12], (const float*)d_in[17]};
    const float* fcw = (const float*)d_in[18];
    const float* fcb = (const float*)d_in[19];
    float* out = (float*)d_out;
    (void)in_sizes; (void)n_in; (void)out_size; (void)ws_size;

    // workspace carve-up (~230 MB)
    char* w = (char*)d_ws;
    size_t off = 0;
    auto carve = [&](size_t bytes) -> void* {
        void* p = (void*)(w + off);
        off += (bytes + 255) & ~(size_t)255;
        return p;
    };
    int*    degi   = (int*)carve((size_t)NN * 4);
    int*    cursor = (int*)carve((size_t)NN * 4);
    float4* edat   = (float4*)carve((size_t)NE * 16);
    float*  S      = (float*)carve((size_t)NN * 192 * 4);   // A buffer, max 3*CINP=192
    int*    bsum   = (int*)carve(1024 * 4);
    float*  Wc     = (float*)carve((size_t)256 * 64 * 4);
    float*  xp     = (float*)carve((size_t)NN * 32 * 4);    // padded input [N,32]
    float*  hA     = (float*)carve((size_t)NN * 32 * 4);    // layer-0 out [N,32]
    float*  hB     = (float*)carve((size_t)NN * 64 * 4);    // layer-1 out [N,64]
    // xp/hA are adjacent 256-aligned carves (each a multiple of 256 B) forming a
    // contiguous [N,64] region that is dead after layer 1 -> reuse as layer-2 out.
    float*  hC     = xp;

    const int* src = ei;
    const int* dst = ei + NE;
    const int EB = (NE + 255) / 256;
    const int GB = (NN + 63) / 64;   // 2561 blocks: 64 rows per block

    // ---- CSR build (once per call) ----
    hipMemsetAsync(degi, 0, (size_t)NN * 4, stream);
    deg_count<<<EB, 256, 0, stream>>>(dst, degi, NE);
    scan1<<<NB, 256, 0, stream>>>(degi, cursor, bsum, NN);
    scan2<<<1, 1024, 0, stream>>>(bsum, NB);
    scan3<<<NB, 256, 0, stream>>>(cursor, bsum, NN);
    scatter_k<<<EB, 256, 0, stream>>>(src, dst, ea, cursor, edat, NE);
    pad_x<<<(NN * 32 + 255) / 256, 256, 0, stream>>>(x, xp, NN);

    // ---- layer 0: 22(pad32) -> 32  (A = [N,96], CW=8: no wasted FMAs) ----
    aggregate_g<32><<<1024, 256, 0, stream>>>(xp, 32, edat, mu_[0], sg_[0], cursor, degi, S, NN);
    build_wc<22, 32, 32><<<32, 256, 0, stream>>>(g_[0], rt_[0], Wc);
    rowgemm_c<96, 32, 8><<<GB, 256, 0, stream>>>(S, xp, 32, Wc, bs_[0], 32, hA, NN);

    // ---- layer 1: 32 -> 64  (A = [N,96]) ----
    aggregate_g<32><<<1024, 256, 0, stream>>>(hA, 32, edat, mu_[1], sg_[1], cursor, degi, S, NN);
    build_wc<32, 32, 64><<<32, 256, 0, stream>>>(g_[1], rt_[1], Wc);
    rowgemm_c<96, 32, 16><<<GB, 256, 0, stream>>>(S, hA, 32, Wc, bs_[1], 64, hB, NN);

    // ---- layer 2: 64 -> 64  (A = [N,192]; out -> hC, distinct from h=hB) ----
    aggregate_g<64><<<2048, 256, 0, stream>>>(hB, 64, edat, mu_[2], sg_[2], cursor, degi, S, NN);
    build_wc<64, 64, 64><<<64, 256, 0, stream>>>(g_[2], rt_[2], Wc);
    rowgemm_c<192, 64, 16><<<GB, 256, 0, stream>>>(S, hB, 64, Wc, bs_[2], 64, hC, NN);

    final_kernel<<<(NN + 255) / 256, 256, 0, stream>>>(hC, fcw, fcb, out, NN);
}

// Round 15
// 441.373 us; speedup vs baseline: 1.3129x; 1.1670x over previous
//
#include <hip/hip_runtime.h>

#define NN 163842
#define NE 983040
#define NB 641   // ceil(NN/256)

// ---------------- degree count (int) ----------------
__global__ __launch_bounds__(256) void deg_count(const int* __restrict__ dst,
                                                 int* __restrict__ degi, int E) {
    int e = blockIdx.x * 256 + threadIdx.x;
    if (e < E) atomicAdd(&degi[dst[e]], 1);
}

// ---------------- exclusive scan of degi -> cursor ----------------
__global__ __launch_bounds__(256) void scan1(const int* __restrict__ degi,
                                             int* __restrict__ cursor,
                                             int* __restrict__ bsum, int n) {
    __shared__ int tmp[256];
    int t = threadIdx.x;
    int i = blockIdx.x * 256 + t;
    int v = (i < n) ? degi[i] : 0;
    tmp[t] = v;
    __syncthreads();
    for (int o = 1; o < 256; o <<= 1) {
        int x = (t >= o) ? tmp[t - o] : 0;
        __syncthreads();
        tmp[t] += x;
        __syncthreads();
    }
    if (i < n) cursor[i] = tmp[t] - v;            // exclusive
    if (t == 255) bsum[blockIdx.x] = tmp[255];    // block total
}

__global__ void scan2(int* __restrict__ bsum, int nb) {
    __shared__ int tmp[1024];
    int t = threadIdx.x;
    int v = (t < nb) ? bsum[t] : 0;
    tmp[t] = v;
    __syncthreads();
    for (int o = 1; o < 1024; o <<= 1) {
        int x = (t >= o) ? tmp[t - o] : 0;
        __syncthreads();
        tmp[t] += x;
        __syncthreads();
    }
    if (t < nb) bsum[t] = tmp[t] - v;
}

__global__ __launch_bounds__(256) void scan3(int* __restrict__ cursor,
                                             const int* __restrict__ bsum, int n) {
    int i = blockIdx.x * 256 + threadIdx.x;
    if (i < n) cursor[i] += bsum[blockIdx.x];
}

// ---------------- scatter: permute edges into dst-sorted order ----------------
// edat[p] = {src (bits), ea.x, ea.y, 0} — one 16-B record per edge
__global__ __launch_bounds__(256) void scatter_k(const int* __restrict__ src,
                                                 const int* __restrict__ dst,
                                                 const float* __restrict__ ea,
                                                 int* __restrict__ cursor,
                                                 float4* __restrict__ edat, int E) {
    int e = blockIdx.x * 256 + threadIdx.x;
    if (e >= E) return;
    int p = atomicAdd(&cursor[dst[e]], 1);
    edat[p] = make_float4(__int_as_float(src[e]), ea[2 * e], ea[2 * e + 1], 0.0f);
}

// ---------------- pad x [N,22] -> xp [N,32] ----------------
__global__ __launch_bounds__(256) void pad_x(const float* __restrict__ x,
                                             float* __restrict__ xp, int n) {
    int t = blockIdx.x * 256 + threadIdx.x;
    if (t >= n * 32) return;
    int r = t >> 5, c = t & 31;
    xp[t] = (c < 22) ? x[r * 22 + c] : 0.0f;
}

// ---------------- build Wc[4*CINP, 64] = [g0;g1;g2;root], zero-padded ----------------
template <int CIN, int CINP, int COUTR>
__global__ __launch_bounds__(256) void build_wc(const float* __restrict__ g,
                                                const float* __restrict__ root,
                                                float* __restrict__ Wc) {
    int t = blockIdx.x * 256 + threadIdx.x;
    constexpr int KTOT = 4 * CINP;
    if (t >= KTOT * 64) return;
    int kt = t >> 6, o = t & 63;
    int k = kt / CINP, c = kt % CINP;
    float v = 0.0f;
    if (c < CIN && o < COUTR)
        v = (k < 3) ? g[c * (3 * COUTR) + k * COUTR + o] : root[c * COUTR + o];
    Wc[t] = v;
}

static __device__ __forceinline__ void fma4(float4& a, float g, const float4& hv) {
    a.x = fmaf(g, hv.x, a.x);
    a.y = fmaf(g, hv.y, a.y);
    a.z = fmaf(g, hv.z, a.z);
    a.w = fmaf(g, hv.w, a.w);
}

static __device__ __forceinline__ unsigned short bf16rne(float x) {
    unsigned u = __float_as_uint(x);
    u += 0x7FFFu + ((u >> 16) & 1u);      // round-to-nearest-even
    return (unsigned short)(u >> 16);
}

// ============ FUSED layer: gaussian aggregate -> LDS tile -> GEMM -> relu ============
// Block = 64 nodes. Phase 1: LPN=CINP/4 lanes per node gather h[src] rows (float4/lane
// /edge), accumulate 3 gaussian-weighted sums in regs, write the 64x(3*CINP) S-tile
// straight into LDS (no global S round-trip — was 2x126 MB at layer 2). Tile stored
// bf16 (BF16=1, layer 2: 192 cols) or fp32 (layers 0/1: 96 cols); both = 25-float4
// odd stride = 25.6 KB -> 6 blocks/CU, conflict-free b128. Phase 2: proven rowgemm_c
// compute: lane=row, wave=CW-col strip, W rows wave-uniform -> s_load broadcast;
// then h-tile restaged into the dead LDS for the root part. No register prefetch
// (always spilled, rounds 11-13). NOTE: out must NOT alias h.
template <int CINP, int CW, bool BF16>
__global__ __launch_bounds__(256) void fused_layer(const float* __restrict__ h, int hs,
                                                   const float4* __restrict__ edat,
                                                   const float* __restrict__ mu,
                                                   const float* __restrict__ sigma,
                                                   const int* __restrict__ cursor,
                                                   const int* __restrict__ degi,
                                                   const float* __restrict__ Wc,
                                                   const float* __restrict__ bias,
                                                   int coutr, float* __restrict__ out, int n) {
    __shared__ float4 sa[64 * 25];               // 25.6 KB
    const int row0 = blockIdx.x * 64;

    // ---------------- phase 1: aggregate into LDS tile ----------------
    {
        float m0x = mu[0], m0y = mu[1], m1x = mu[2], m1y = mu[3], m2x = mu[4], m2y = mu[5];
        float i0x = 1.0f / (1e-15f + sigma[0] * sigma[0]);
        float i0y = 1.0f / (1e-15f + sigma[1] * sigma[1]);
        float i1x = 1.0f / (1e-15f + sigma[2] * sigma[2]);
        float i1y = 1.0f / (1e-15f + sigma[3] * sigma[3]);
        float i2x = 1.0f / (1e-15f + sigma[4] * sigma[4]);
        float i2y = 1.0f / (1e-15f + sigma[5] * sigma[5]);
        constexpr int LPN = CINP / 4;            // lanes per node (8 or 16)
        constexpr int NPP = 256 / LPN;           // nodes per pass (32 or 16)
        const int sub = threadIdx.x / LPN;       // node stream in pass
        const int li  = threadIdx.x % LPN;       // float4 index within row
#pragma unroll
        for (int pass = 0; pass < 64 / NPP; ++pass) {
            int lr = pass * NPP + sub;           // local row
            int node = row0 + lr; if (node > n - 1) node = n - 1;
            int end = cursor[node];
            int dg  = degi[node];
            int p   = end - dg;
            float4 a0 = {0, 0, 0, 0}, a1 = {0, 0, 0, 0}, a2 = {0, 0, 0, 0};
            for (; p + 4 <= end; p += 4) {
                float4 ed[4], hv[4];
#pragma unroll
                for (int u = 0; u < 4; ++u) ed[u] = edat[p + u];
#pragma unroll
                for (int u = 0; u < 4; ++u)
                    hv[u] = ((const float4*)(h + (long)__float_as_int(ed[u].x) * hs))[li];
#pragma unroll
                for (int u = 0; u < 4; ++u) {
                    float dx, dy;
                    dx = ed[u].y - m0x; dy = ed[u].z - m0y;
                    float g0 = __expf(-0.5f * (dx * dx * i0x + dy * dy * i0y));
                    dx = ed[u].y - m1x; dy = ed[u].z - m1y;
                    float g1 = __expf(-0.5f * (dx * dx * i1x + dy * dy * i1y));
                    dx = ed[u].y - m2x; dy = ed[u].z - m2y;
                    float g2 = __expf(-0.5f * (dx * dx * i2x + dy * dy * i2y));
                    fma4(a0, g0, hv[u]);
                    fma4(a1, g1, hv[u]);
                    fma4(a2, g2, hv[u]);
                }
            }
            for (; p < end; ++p) {
                float4 ed = edat[p];
                float4 hv = ((const float4*)(h + (long)__float_as_int(ed.x) * hs))[li];
                float dx, dy;
                dx = ed.y - m0x; dy = ed.z - m0y;
                float g0 = __expf(-0.5f * (dx * dx * i0x + dy * dy * i0y));
                dx = ed.y - m1x; dy = ed.z - m1y;
                float g1 = __expf(-0.5f * (dx * dx * i1x + dy * dy * i1y));
                dx = ed.y - m2x; dy = ed.z - m2y;
                float g2 = __expf(-0.5f * (dx * dx * i2x + dy * dy * i2y));
                fma4(a0, g0, hv);
                fma4(a1, g1, hv);
                fma4(a2, g2, hv);
            }
            float inv = 1.0f / (float)max(dg, 1);
            fma4(a0, inv - 1.0f, a0);   // a0 *= inv (via a0 += (inv-1)*a0)
            fma4(a1, inv - 1.0f, a1);
            fma4(a2, inv - 1.0f, a2);
            int c4b = li * 4;
            if (BF16) {
                unsigned short* st = (unsigned short*)sa;
                int base = lr * 200;             // 400 B row stride
                float4 aa[3] = {a0, a1, a2};
#pragma unroll
                for (int k = 0; k < 3; ++k) {
                    ushort4 v;
                    v.x = bf16rne(aa[k].x); v.y = bf16rne(aa[k].y);
                    v.z = bf16rne(aa[k].z); v.w = bf16rne(aa[k].w);
                    *(ushort4*)(st + base + k * CINP + c4b) = v;
                }
            } else {
                float* stf = (float*)sa;
                int base = lr * 100;             // 400 B row stride
                *(float4*)(stf + base + 0 * CINP + c4b) = a0;
                *(float4*)(stf + base + 1 * CINP + c4b) = a1;
                *(float4*)(stf + base + 2 * CINP + c4b) = a2;
            }
        }
    }
    __syncthreads();

    // ---------------- phase 2: GEMM from LDS tile ----------------
    const int lane = threadIdx.x & 63;           // local row
    const int wid  = __builtin_amdgcn_readfirstlane(threadIdx.x >> 6);
    const int cb   = wid * CW;                   // column strip base
    const int row  = row0 + lane;
    const bool valid = (row < n) && (cb < coutr);
    float acc[CW];
#pragma unroll
    for (int c = 0; c < CW; ++c) acc[c] = 0.0f;

    // S part: 24 float4 reads per row cover 3*CINP k's (8 bf16 or 4 fp32 per read)
#pragma unroll 2
    for (int k4 = 0; k4 < 24; ++k4) {
        float4 a = sa[lane * 25 + k4];
        if (BF16) {
            unsigned uu[4] = {__float_as_uint(a.x), __float_as_uint(a.y),
                              __float_as_uint(a.z), __float_as_uint(a.w)};
#pragma unroll
            for (int i = 0; i < 4; ++i) {
                float f0 = __uint_as_float(uu[i] << 16);
                float f1 = __uint_as_float(uu[i] & 0xFFFF0000u);
                const float* w0 = Wc + (8 * k4 + 2 * i) * 64 + cb;      // s_load
                const float* w1 = Wc + (8 * k4 + 2 * i + 1) * 64 + cb;
#pragma unroll
                for (int c = 0; c < CW; ++c) acc[c] = fmaf(f0, w0[c], acc[c]);
#pragma unroll
                for (int c = 0; c < CW; ++c) acc[c] = fmaf(f1, w1[c], acc[c]);
            }
        } else {
            float av[4] = {a.x, a.y, a.z, a.w};
#pragma unroll
            for (int j = 0; j < 4; ++j) {
                const float* wrow = Wc + (4 * k4 + j) * 64 + cb;        // s_load
#pragma unroll
                for (int c = 0; c < CW; ++c) acc[c] = fmaf(av[j], wrow[c], acc[c]);
            }
        }
    }
    // h (root) part: restage h tile into the now-dead LDS
    constexpr int KH4 = CINP / 4;
    __syncthreads();
    for (int f = threadIdx.x; f < 64 * KH4; f += 256) {
        int r = f / KH4, c4 = f - (f / KH4) * KH4;
        int gr = row0 + r; if (gr > n - 1) gr = n - 1;
        sa[r * 25 + c4] = ((const float4*)(h + (long)gr * hs))[c4];
    }
    __syncthreads();
#pragma unroll 2
    for (int k4 = 0; k4 < KH4; ++k4) {
        float4 a = sa[lane * 25 + k4];
        float av[4] = {a.x, a.y, a.z, a.w};
#pragma unroll
        for (int j = 0; j < 4; ++j) {
            const float* wrow = Wc + ((3 * CINP + 4 * k4 + j)) * 64 + cb;
#pragma unroll
            for (int c = 0; c < CW; ++c) acc[c] = fmaf(av[j], wrow[c], acc[c]);
        }
    }
    if (valid) {
        const float* bh = bias + cb;
        float4* o4 = (float4*)(out + (long)row * coutr + cb);
#pragma unroll
        for (int c4 = 0; c4 < CW / 4; ++c4) {
            float4 v;
            v.x = fmaxf(acc[4 * c4 + 0] + bh[4 * c4 + 0], 0.0f);
            v.y = fmaxf(acc[4 * c4 + 1] + bh[4 * c4 + 1], 0.0f);
            v.z = fmaxf(acc[4 * c4 + 2] + bh[4 * c4 + 2], 0.0f);
            v.w = fmaxf(acc[4 * c4 + 3] + bh[4 * c4 + 3], 0.0f);
            o4[c4] = v;
        }
    }
}

// ---------------- final FC (64->2) + log_softmax ----------------
__global__ __launch_bounds__(256) void final_kernel(const float* __restrict__ h,
                                                    const float* __restrict__ fcw,
                                                    const float* __restrict__ fcb,
                                                    float* __restrict__ out, int n) {
    int i = blockIdx.x * 256 + threadIdx.x;
    if (i >= n) return;
    const float4* h4 = (const float4*)(h + (long)i * 64);
    float l0 = fcb[0];
    float l1 = fcb[1];
#pragma unroll
    for (int j4 = 0; j4 < 16; ++j4) {
        float4 hv = h4[j4];
        l0 = fmaf(hv.x, fcw[8 * j4 + 0], l0);
        l1 = fmaf(hv.x, fcw[8 * j4 + 1], l1);
        l0 = fmaf(hv.y, fcw[8 * j4 + 2], l0);
        l1 = fmaf(hv.y, fcw[8 * j4 + 3], l1);
        l0 = fmaf(hv.z, fcw[8 * j4 + 4], l0);
        l1 = fmaf(hv.z, fcw[8 * j4 + 5], l1);
        l0 = fmaf(hv.w, fcw[8 * j4 + 6], l0);
        l1 = fmaf(hv.w, fcw[8 * j4 + 7], l1);
    }
    float mx  = fmaxf(l0, l1);
    float lse = mx + logf(__expf(l0 - mx) + __expf(l1 - mx));
    out[2 * (long)i]     = l0 - lse;
    out[2 * (long)i + 1] = l1 - lse;
}

extern "C" void kernel_launch(void* const* d_in, const int* in_sizes, int n_in,
                              void* d_out, int out_size, void* d_ws, size_t ws_size,
                              hipStream_t stream) {
    const float* x   = (const float*)d_in[0];
    const int*   ei  = (const int*)d_in[1];
    const float* ea  = (const float*)d_in[2];
    const float* g_[3]  = {(const float*)d_in[3],  (const float*)d_in[8],  (const float*)d_in[13]};
    const float* mu_[3] = {(const float*)d_in[4],  (const float*)d_in[9],  (const float*)d_in[14]};
    const float* sg_[3] = {(const float*)d_in[5],  (const float*)d_in[10], (const float*)d_in[15]};
    const float* rt_[3] = {(const float*)d_in[6],  (const float*)d_in[11], (const float*)d_in[16]};
    const float* bs_[3] = {(const float*)d_in[7],  (const float*)d_in[12], (const float*)d_in[17]};
    const float* fcw = (const float*)d_in[18];
    const float* fcb = (const float*)d_in[19];
    float* out = (float*)d_out;
    (void)in_sizes; (void)n_in; (void)out_size; (void)ws_size;

    // workspace carve-up (~100 MB)
    char* w = (char*)d_ws;
    size_t off = 0;
    auto carve = [&](size_t bytes) -> void* {
        void* p = (void*)(w + off);
        off += (bytes + 255) & ~(size_t)255;
        return p;
    };
    int*    degi   = (int*)carve((size_t)NN * 4);
    int*    cursor = (int*)carve((size_t)NN * 4);
    float4* edat   = (float4*)carve((size_t)NE * 16);
    int*    bsum   = (int*)carve(1024 * 4);
    float*  Wc     = (float*)carve((size_t)256 * 64 * 4);
    float*  xp     = (float*)carve((size_t)NN * 32 * 4);    // padded input [N,32]
    float*  hA     = (float*)carve((size_t)NN * 32 * 4);    // layer-0 out [N,32]
    float*  hB     = (float*)carve((size_t)NN * 64 * 4);    // layer-1 out [N,64]
    // xp/hA are adjacent 256-aligned carves (each a multiple of 256 B) forming a
    // contiguous [N,64] region that is dead after layer 1 -> reuse as layer-2 out.
    float*  hC     = xp;

    const int* src = ei;
    const int* dst = ei + NE;
    const int EB = (NE + 255) / 256;
    const int GB = (NN + 63) / 64;   // 2561 blocks: 64 nodes per block

    // ---- CSR build (once per call) ----
    hipMemsetAsync(degi, 0, (size_t)NN * 4, stream);
    deg_count<<<EB, 256, 0, stream>>>(dst, degi, NE);
    scan1<<<NB, 256, 0, stream>>>(degi, cursor, bsum, NN);
    scan2<<<1, 1024, 0, stream>>>(bsum, NB);
    scan3<<<NB, 256, 0, stream>>>(cursor, bsum, NN);
    scatter_k<<<EB, 256, 0, stream>>>(src, dst, ea, cursor, edat, NE);
    pad_x<<<(NN * 32 + 255) / 256, 256, 0, stream>>>(x, xp, NN);

    // ---- layer 0: 22(pad32) -> 32 (fp32 tile, CW=8: no wasted FMAs) ----
    build_wc<22, 32, 32><<<32, 256, 0, stream>>>(g_[0], rt_[0], Wc);
    fused_layer<32, 8, false><<<GB, 256, 0, stream>>>(xp, 32, edat, mu_[0], sg_[0],
                                                      cursor, degi, Wc, bs_[0], 32, hA, NN);

    // ---- layer 1: 32 -> 64 (fp32 tile) ----
    build_wc<32, 32, 64><<<32, 256, 0, stream>>>(g_[1], rt_[1], Wc);
    fused_layer<32, 16, false><<<GB, 256, 0, stream>>>(hA, 32, edat, mu_[1], sg_[1],
                                                       cursor, degi, Wc, bs_[1], 64, hB, NN);

    // ---- layer 2: 64 -> 64 (bf16 tile: 192 cols in 25.6 KB; out hC != h hB) ----
    build_wc<64, 64, 64><<<64, 256, 0, stream>>>(g_[2], rt_[2], Wc);
    fused_layer<64, 16, true><<<GB, 256, 0, stream>>>(hB, 64, edat, mu_[2], sg_[2],
                                                      cursor, degi, Wc, bs_[2], 64, hC, NN);

    final_kernel<<<(NN + 255) / 256, 256, 0, stream>>>(hC, fcw, fcb, out, NN);
}

// Round 16
// 439.858 us; speedup vs baseline: 1.3174x; 1.0034x over previous
//
#include <hip/hip_runtime.h>

#define NN 163842
#define NE 983040
#define NB 641   // ceil(NN/256)

// ---------------- degree count (int) ----------------
__global__ __launch_bounds__(256) void deg_count(const int* __restrict__ dst,
                                                 int* __restrict__ degi, int E) {
    int e = blockIdx.x * 256 + threadIdx.x;
    if (e < E) atomicAdd(&degi[dst[e]], 1);
}

// ---------------- exclusive scan of degi -> cursor ----------------
__global__ __launch_bounds__(256) void scan1(const int* __restrict__ degi,
                                             int* __restrict__ cursor,
                                             int* __restrict__ bsum, int n) {
    __shared__ int tmp[256];
    int t = threadIdx.x;
    int i = blockIdx.x * 256 + t;
    int v = (i < n) ? degi[i] : 0;
    tmp[t] = v;
    __syncthreads();
    for (int o = 1; o < 256; o <<= 1) {
        int x = (t >= o) ? tmp[t - o] : 0;
        __syncthreads();
        tmp[t] += x;
        __syncthreads();
    }
    if (i < n) cursor[i] = tmp[t] - v;            // exclusive
    if (t == 255) bsum[blockIdx.x] = tmp[255];    // block total
}

__global__ void scan2(int* __restrict__ bsum, int nb) {
    __shared__ int tmp[1024];
    int t = threadIdx.x;
    int v = (t < nb) ? bsum[t] : 0;
    tmp[t] = v;
    __syncthreads();
    for (int o = 1; o < 1024; o <<= 1) {
        int x = (t >= o) ? tmp[t - o] : 0;
        __syncthreads();
        tmp[t] += x;
        __syncthreads();
    }
    if (t < nb) bsum[t] = tmp[t] - v;
}

__global__ __launch_bounds__(256) void scan3(int* __restrict__ cursor,
                                             const int* __restrict__ bsum, int n) {
    int i = blockIdx.x * 256 + threadIdx.x;
    if (i < n) cursor[i] += bsum[blockIdx.x];
}

static __device__ __forceinline__ float3 gauss3(float ex, float ey,
                                                const float* __restrict__ mu,
                                                const float* __restrict__ sg) {
    float3 r;
    float dx, dy;
    dx = ex - mu[0]; dy = ey - mu[1];
    r.x = __expf(-0.5f * (dx * dx / (1e-15f + sg[0] * sg[0]) + dy * dy / (1e-15f + sg[1] * sg[1])));
    dx = ex - mu[2]; dy = ey - mu[3];
    r.y = __expf(-0.5f * (dx * dx / (1e-15f + sg[2] * sg[2]) + dy * dy / (1e-15f + sg[3] * sg[3])));
    dx = ex - mu[4]; dy = ey - mu[5];
    r.z = __expf(-0.5f * (dx * dx / (1e-15f + sg[4] * sg[4]) + dy * dy / (1e-15f + sg[5] * sg[5])));
    return r;
}

// ---- scatter + ALL per-layer gaussians: ged[l][p] = {src_bits, g0, g1, g2} ----
// Gaussians depend only on (edge, layer): compute once here, not per fused layer
// (was ~21 VALU issues/edge/layer inside fused phase 1 — round 15's top cost).
__global__ __launch_bounds__(256) void scatter_g(const int* __restrict__ src,
                                                 const int* __restrict__ dst,
                                                 const float* __restrict__ ea,
                                                 int* __restrict__ cursor,
                                                 const float* __restrict__ mu0, const float* __restrict__ sg0,
                                                 const float* __restrict__ mu1, const float* __restrict__ sg1,
                                                 const float* __restrict__ mu2, const float* __restrict__ sg2,
                                                 float4* __restrict__ g0b,
                                                 float4* __restrict__ g1b,
                                                 float4* __restrict__ g2b, int E) {
    int e = blockIdx.x * 256 + threadIdx.x;
    if (e >= E) return;
    int p = atomicAdd(&cursor[dst[e]], 1);
    float ex = ea[2 * e], ey = ea[2 * e + 1];
    float sb = __int_as_float(src[e]);
    float3 g0 = gauss3(ex, ey, mu0, sg0);
    float3 g1 = gauss3(ex, ey, mu1, sg1);
    float3 g2 = gauss3(ex, ey, mu2, sg2);
    g0b[p] = make_float4(sb, g0.x, g0.y, g0.z);
    g1b[p] = make_float4(sb, g1.x, g1.y, g1.z);
    g2b[p] = make_float4(sb, g2.x, g2.y, g2.z);
}

// ---------------- pad x [N,22] -> xp [N,32] ----------------
__global__ __launch_bounds__(256) void pad_x(const float* __restrict__ x,
                                             float* __restrict__ xp, int n) {
    int t = blockIdx.x * 256 + threadIdx.x;
    if (t >= n * 32) return;
    int r = t >> 5, c = t & 31;
    xp[t] = (c < 22) ? x[r * 22 + c] : 0.0f;
}

// ---------------- build Wc[4*CINP, 64] = [g0;g1;g2;root], zero-padded ----------------
template <int CIN, int CINP, int COUTR>
__global__ __launch_bounds__(256) void build_wc(const float* __restrict__ g,
                                                const float* __restrict__ root,
                                                float* __restrict__ Wc) {
    int t = blockIdx.x * 256 + threadIdx.x;
    constexpr int KTOT = 4 * CINP;
    if (t >= KTOT * 64) return;
    int kt = t >> 6, o = t & 63;
    int k = kt / CINP, c = kt % CINP;
    float v = 0.0f;
    if (c < CIN && o < COUTR)
        v = (k < 3) ? g[c * (3 * COUTR) + k * COUTR + o] : root[c * COUTR + o];
    Wc[t] = v;
}

static __device__ __forceinline__ void fma4(float4& a, float g, const float4& hv) {
    a.x = fmaf(g, hv.x, a.x);
    a.y = fmaf(g, hv.y, a.y);
    a.z = fmaf(g, hv.z, a.z);
    a.w = fmaf(g, hv.w, a.w);
}

static __device__ __forceinline__ unsigned short bf16rne(float x) {
    unsigned u = __float_as_uint(x);
    u += 0x7FFFu + ((u >> 16) & 1u);      // round-to-nearest-even
    return (unsigned short)(u >> 16);
}

// ============ FUSED layer: aggregate (precomputed gauss) -> LDS tile -> GEMM ============
// Block = 64 nodes. Phase 1: LPN=CINP/4 lanes per node; per edge: 1 record load
// {src,g0,g1,g2} + 1 float4 h-gather + 12 FMA — no exp (hoisted to scatter_g).
// Tile bf16 (layer 2) / fp32 (layers 0/1), 64 rows x 25 float4 odd stride = 25.6 KB
// -> 6 blocks/CU, conflict-free b128. Phase 2: lane=row, wave=CW-col strip,
// W rows wave-uniform -> s_load broadcast; h restaged for root part.
// No register prefetch (spilled in rounds 11-13). NOTE: out must NOT alias h.
template <int CINP, int CW, bool BF16>
__global__ __launch_bounds__(256) void fused_layer(const float* __restrict__ h, int hs,
                                                   const float4* __restrict__ ged,
                                                   const int* __restrict__ cursor,
                                                   const int* __restrict__ degi,
                                                   const float* __restrict__ Wc,
                                                   const float* __restrict__ bias,
                                                   int coutr, float* __restrict__ out, int n) {
    __shared__ float4 sa[64 * 25];               // 25.6 KB
    const int row0 = blockIdx.x * 64;

    // ---------------- phase 1: aggregate into LDS tile ----------------
    {
        constexpr int LPN = CINP / 4;            // lanes per node (8 or 16)
        constexpr int NPP = 256 / LPN;           // nodes per pass (32 or 16)
        const int sub = threadIdx.x / LPN;       // node stream in pass
        const int li  = threadIdx.x % LPN;       // float4 index within row
#pragma unroll
        for (int pass = 0; pass < 64 / NPP; ++pass) {
            int lr = pass * NPP + sub;           // local row
            int node = row0 + lr; if (node > n - 1) node = n - 1;
            int end = cursor[node];
            int dg  = degi[node];
            int p   = end - dg;
            float4 a0 = {0, 0, 0, 0}, a1 = {0, 0, 0, 0}, a2 = {0, 0, 0, 0};
            for (; p + 4 <= end; p += 4) {
                float4 ed[4], hv[4];
#pragma unroll
                for (int u = 0; u < 4; ++u) ed[u] = ged[p + u];
#pragma unroll
                for (int u = 0; u < 4; ++u)
                    hv[u] = ((const float4*)(h + (long)__float_as_int(ed[u].x) * hs))[li];
#pragma unroll
                for (int u = 0; u < 4; ++u) {
                    fma4(a0, ed[u].y, hv[u]);
                    fma4(a1, ed[u].z, hv[u]);
                    fma4(a2, ed[u].w, hv[u]);
                }
            }
            for (; p < end; ++p) {
                float4 ed = ged[p];
                float4 hv = ((const float4*)(h + (long)__float_as_int(ed.x) * hs))[li];
                fma4(a0, ed.y, hv);
                fma4(a1, ed.z, hv);
                fma4(a2, ed.w, hv);
            }
            float inv = 1.0f / (float)max(dg, 1);
            fma4(a0, inv - 1.0f, a0);   // a *= inv
            fma4(a1, inv - 1.0f, a1);
            fma4(a2, inv - 1.0f, a2);
            int c4b = li * 4;
            if (BF16) {
                unsigned short* st = (unsigned short*)sa;
                int base = lr * 200;             // 400 B row stride
                float4 aa[3] = {a0, a1, a2};
#pragma unroll
                for (int k = 0; k < 3; ++k) {
                    ushort4 v;
                    v.x = bf16rne(aa[k].x); v.y = bf16rne(aa[k].y);
                    v.z = bf16rne(aa[k].z); v.w = bf16rne(aa[k].w);
                    *(ushort4*)(st + base + k * CINP + c4b) = v;
                }
            } else {
                float* stf = (float*)sa;
                int base = lr * 100;             // 400 B row stride
                *(float4*)(stf + base + 0 * CINP + c4b) = a0;
                *(float4*)(stf + base + 1 * CINP + c4b) = a1;
                *(float4*)(stf + base + 2 * CINP + c4b) = a2;
            }
        }
    }
    __syncthreads();

    // ---------------- phase 2: GEMM from LDS tile ----------------
    const int lane = threadIdx.x & 63;           // local row
    const int wid  = __builtin_amdgcn_readfirstlane(threadIdx.x >> 6);
    const int cb   = wid * CW;                   // column strip base
    const int row  = row0 + lane;
    const bool valid = (row < n) && (cb < coutr);
    float acc[CW];
#pragma unroll
    for (int c = 0; c < CW; ++c) acc[c] = 0.0f;

    // S part: 24 float4 reads per row cover 3*CINP k's (8 bf16 or 4 fp32 per read)
#pragma unroll 2
    for (int k4 = 0; k4 < 24; ++k4) {
        float4 a = sa[lane * 25 + k4];
        if (BF16) {
            unsigned uu[4] = {__float_as_uint(a.x), __float_as_uint(a.y),
                              __float_as_uint(a.z), __float_as_uint(a.w)};
#pragma unroll
            for (int i = 0; i < 4; ++i) {
                float f0 = __uint_as_float(uu[i] << 16);
                float f1 = __uint_as_float(uu[i] & 0xFFFF0000u);
                const float* w0 = Wc + (8 * k4 + 2 * i) * 64 + cb;      // s_load
                const float* w1 = Wc + (8 * k4 + 2 * i + 1) * 64 + cb;
#pragma unroll
                for (int c = 0; c < CW; ++c) acc[c] = fmaf(f0, w0[c], acc[c]);
#pragma unroll
                for (int c = 0; c < CW; ++c) acc[c] = fmaf(f1, w1[c], acc[c]);
            }
        } else {
            float av[4] = {a.x, a.y, a.z, a.w};
#pragma unroll
            for (int j = 0; j < 4; ++j) {
                const float* wrow = Wc + (4 * k4 + j) * 64 + cb;        // s_load
#pragma unroll
                for (int c = 0; c < CW; ++c) acc[c] = fmaf(av[j], wrow[c], acc[c]);
            }
        }
    }
    // h (root) part: restage h tile into the now-dead LDS
    constexpr int KH4 = CINP / 4;
    __syncthreads();
    for (int f = threadIdx.x; f < 64 * KH4; f += 256) {
        int r = f / KH4, c4 = f - (f / KH4) * KH4;
        int gr = row0 + r; if (gr > n - 1) gr = n - 1;
        sa[r * 25 + c4] = ((const float4*)(h + (long)gr * hs))[c4];
    }
    __syncthreads();
#pragma unroll 2
    for (int k4 = 0; k4 < KH4; ++k4) {
        float4 a = sa[lane * 25 + k4];
        float av[4] = {a.x, a.y, a.z, a.w};
#pragma unroll
        for (int j = 0; j < 4; ++j) {
            const float* wrow = Wc + ((3 * CINP + 4 * k4 + j)) * 64 + cb;
#pragma unroll
            for (int c = 0; c < CW; ++c) acc[c] = fmaf(av[j], wrow[c], acc[c]);
        }
    }
    if (valid) {
        const float* bh = bias + cb;
        float4* o4 = (float4*)(out + (long)row * coutr + cb);
#pragma unroll
        for (int c4 = 0; c4 < CW / 4; ++c4) {
            float4 v;
            v.x = fmaxf(acc[4 * c4 + 0] + bh[4 * c4 + 0], 0.0f);
            v.y = fmaxf(acc[4 * c4 + 1] + bh[4 * c4 + 1], 0.0f);
            v.z = fmaxf(acc[4 * c4 + 2] + bh[4 * c4 + 2], 0.0f);
            v.w = fmaxf(acc[4 * c4 + 3] + bh[4 * c4 + 3], 0.0f);
            o4[c4] = v;
        }
    }
}

// ---------------- final FC (64->2) + log_softmax ----------------
__global__ __launch_bounds__(256) void final_kernel(const float* __restrict__ h,
                                                    const float* __restrict__ fcw,
                                                    const float* __restrict__ fcb,
                                                    float* __restrict__ out, int n) {
    int i = blockIdx.x * 256 + threadIdx.x;
    if (i >= n) return;
    const float4* h4 = (const float4*)(h + (long)i * 64);
    float l0 = fcb[0];
    float l1 = fcb[1];
#pragma unroll
    for (int j4 = 0; j4 < 16; ++j4) {
        float4 hv = h4[j4];
        l0 = fmaf(hv.x, fcw[8 * j4 + 0], l0);
        l1 = fmaf(hv.x, fcw[8 * j4 + 1], l1);
        l0 = fmaf(hv.y, fcw[8 * j4 + 2], l0);
        l1 = fmaf(hv.y, fcw[8 * j4 + 3], l1);
        l0 = fmaf(hv.z, fcw[8 * j4 + 4], l0);
        l1 = fmaf(hv.z, fcw[8 * j4 + 5], l1);
        l0 = fmaf(hv.w, fcw[8 * j4 + 6], l0);
        l1 = fmaf(hv.w, fcw[8 * j4 + 7], l1);
    }
    float mx  = fmaxf(l0, l1);
    float lse = mx + logf(__expf(l0 - mx) + __expf(l1 - mx));
    out[2 * (long)i]     = l0 - lse;
    out[2 * (long)i + 1] = l1 - lse;
}

extern "C" void kernel_launch(void* const* d_in, const int* in_sizes, int n_in,
                              void* d_out, int out_size, void* d_ws, size_t ws_size,
                              hipStream_t stream) {
    const float* x   = (const float*)d_in[0];
    const int*   ei  = (const int*)d_in[1];
    const float* ea  = (const float*)d_in[2];
    const float* g_[3]  = {(const float*)d_in[3],  (const float*)d_in[8],  (const float*)d_in[13]};
    const float* mu_[3] = {(const float*)d_in[4],  (const float*)d_in[9],  (const float*)d_in[14]};
    const float* sg_[3] = {(const float*)d_in[5],  (const float*)d_in[10], (const float*)d_in[15]};
    const float* rt_[3] = {(const float*)d_in[6],  (const float*)d_in[11], (const float*)d_in[16]};
    const float* bs_[3] = {(const float*)d_in[7],  (const float*)d_in[12], (const float*)d_in[17]};
    const float* fcw = (const float*)d_in[18];
    const float* fcb = (const float*)d_in[19];
    float* out = (float*)d_out;
    (void)in_sizes; (void)n_in; (void)out_size; (void)ws_size;

    // workspace carve-up (~85 MB)
    char* w = (char*)d_ws;
    size_t off = 0;
    auto carve = [&](size_t bytes) -> void* {
        void* p = (void*)(w + off);
        off += (bytes + 255) & ~(size_t)255;
        return p;
    };
    int*    degi   = (int*)carve((size_t)NN * 4);
    int*    cursor = (int*)carve((size_t)NN * 4);
    float4* ged0   = (float4*)carve((size_t)NE * 16);
    float4* ged1   = (float4*)carve((size_t)NE * 16);
    float4* ged2   = (float4*)carve((size_t)NE * 16);
    int*    bsum   = (int*)carve(1024 * 4);
    float*  Wc     = (float*)carve((size_t)256 * 64 * 4);
    float*  xp     = (float*)carve((size_t)NN * 32 * 4);    // padded input [N,32]
    float*  hA     = (float*)carve((size_t)NN * 32 * 4);    // layer-0 out [N,32]
    float*  hB     = (float*)carve((size_t)NN * 64 * 4);    // layer-1 out [N,64]
    // xp/hA are adjacent 256-aligned carves (each a multiple of 256 B) forming a
    // contiguous [N,64] region that is dead after layer 1 -> reuse as layer-2 out.
    float*  hC     = xp;

    const int* src = ei;
    const int* dst = ei + NE;
    const int EB = (NE + 255) / 256;
    const int GB = (NN + 63) / 64;   // 2561 blocks: 64 nodes per block

    // ---- CSR build + all-layer gaussians (once per call) ----
    hipMemsetAsync(degi, 0, (size_t)NN * 4, stream);
    deg_count<<<EB, 256, 0, stream>>>(dst, degi, NE);
    scan1<<<NB, 256, 0, stream>>>(degi, cursor, bsum, NN);
    scan2<<<1, 1024, 0, stream>>>(bsum, NB);
    scan3<<<NB, 256, 0, stream>>>(cursor, bsum, NN);
    scatter_g<<<EB, 256, 0, stream>>>(src, dst, ea, cursor,
                                      mu_[0], sg_[0], mu_[1], sg_[1], mu_[2], sg_[2],
                                      ged0, ged1, ged2, NE);
    pad_x<<<(NN * 32 + 255) / 256, 256, 0, stream>>>(x, xp, NN);

    // ---- layer 0: 22(pad32) -> 32 (fp32 tile, CW=8: no wasted FMAs) ----
    build_wc<22, 32, 32><<<32, 256, 0, stream>>>(g_[0], rt_[0], Wc);
    fused_layer<32, 8, false><<<GB, 256, 0, stream>>>(xp, 32, ged0, cursor, degi,
                                                      Wc, bs_[0], 32, hA, NN);

    // ---- layer 1: 32 -> 64 (fp32 tile) ----
    build_wc<32, 32, 64><<<32, 256, 0, stream>>>(g_[1], rt_[1], Wc);
    fused_layer<32, 16, false><<<GB, 256, 0, stream>>>(hA, 32, ged1, cursor, degi,
                                                       Wc, bs_[1], 64, hB, NN);

    // ---- layer 2: 64 -> 64 (bf16 tile: 192 cols in 25.6 KB; out hC != h hB) ----
    build_wc<64, 64, 64><<<64, 256, 0, stream>>>(g_[2], rt_[2], Wc);
    fused_layer<64, 16, true><<<GB, 256, 0, stream>>>(hB, 64, ged2, cursor, degi,
                                                      Wc, bs_[2], 64, hC, NN);

    final_kernel<<<(NN + 255) / 256, 256, 0, stream>>>(hC, fcw, fcb, out, NN);
}

// Round 17
// 424.476 us; speedup vs baseline: 1.3651x; 1.0362x over previous
//
#include <hip/hip_runtime.h>

#define NN 163842
#define NE 983040
#define NB 641   // ceil(NN/256)

using short8 = __attribute__((ext_vector_type(8))) short;
using f32x4  = __attribute__((ext_vector_type(4))) float;

// ---------------- degree count (int) ----------------
__global__ __launch_bounds__(256) void deg_count(const int* __restrict__ dst,
                                                 int* __restrict__ degi, int E) {
    int e = blockIdx.x * 256 + threadIdx.x;
    if (e < E) atomicAdd(&degi[dst[e]], 1);
}

// ---------------- exclusive scan of degi -> cursor ----------------
__global__ __launch_bounds__(256) void scan1(const int* __restrict__ degi,
                                             int* __restrict__ cursor,
                                             int* __restrict__ bsum, int n) {
    __shared__ int tmp[256];
    int t = threadIdx.x;
    int i = blockIdx.x * 256 + t;
    int v = (i < n) ? degi[i] : 0;
    tmp[t] = v;
    __syncthreads();
    for (int o = 1; o < 256; o <<= 1) {
        int x = (t >= o) ? tmp[t - o] : 0;
        __syncthreads();
        tmp[t] += x;
        __syncthreads();
    }
    if (i < n) cursor[i] = tmp[t] - v;            // exclusive
    if (t == 255) bsum[blockIdx.x] = tmp[255];    // block total
}

__global__ void scan2(int* __restrict__ bsum, int nb) {
    __shared__ int tmp[1024];
    int t = threadIdx.x;
    int v = (t < nb) ? bsum[t] : 0;
    tmp[t] = v;
    __syncthreads();
    for (int o = 1; o < 1024; o <<= 1) {
        int x = (t >= o) ? tmp[t - o] : 0;
        __syncthreads();
        tmp[t] += x;
        __syncthreads();
    }
    if (t < nb) bsum[t] = tmp[t] - v;
}

__global__ __launch_bounds__(256) void scan3(int* __restrict__ cursor,
                                             const int* __restrict__ bsum, int n) {
    int i = blockIdx.x * 256 + threadIdx.x;
    if (i < n) cursor[i] += bsum[blockIdx.x];
}

static __device__ __forceinline__ float3 gauss3(float ex, float ey,
                                                const float* __restrict__ mu,
                                                const float* __restrict__ sg) {
    float3 r;
    float dx, dy;
    dx = ex - mu[0]; dy = ey - mu[1];
    r.x = __expf(-0.5f * (dx * dx / (1e-15f + sg[0] * sg[0]) + dy * dy / (1e-15f + sg[1] * sg[1])));
    dx = ex - mu[2]; dy = ey - mu[3];
    r.y = __expf(-0.5f * (dx * dx / (1e-15f + sg[2] * sg[2]) + dy * dy / (1e-15f + sg[3] * sg[3])));
    dx = ex - mu[4]; dy = ey - mu[5];
    r.z = __expf(-0.5f * (dx * dx / (1e-15f + sg[4] * sg[4]) + dy * dy / (1e-15f + sg[5] * sg[5])));
    return r;
}

// ---- scatter + ALL per-layer gaussians: ged[l][p] = {src_bits, g0, g1, g2} ----
__global__ __launch_bounds__(256) void scatter_g(const int* __restrict__ src,
                                                 const int* __restrict__ dst,
                                                 const float* __restrict__ ea,
                                                 int* __restrict__ cursor,
                                                 const float* __restrict__ mu0, const float* __restrict__ sg0,
                                                 const float* __restrict__ mu1, const float* __restrict__ sg1,
                                                 const float* __restrict__ mu2, const float* __restrict__ sg2,
                                                 float4* __restrict__ g0b,
                                                 float4* __restrict__ g1b,
                                                 float4* __restrict__ g2b, int E) {
    int e = blockIdx.x * 256 + threadIdx.x;
    if (e >= E) return;
    int p = atomicAdd(&cursor[dst[e]], 1);
    float ex = ea[2 * e], ey = ea[2 * e + 1];
    float sb = __int_as_float(src[e]);
    float3 g0 = gauss3(ex, ey, mu0, sg0);
    float3 g1 = gauss3(ex, ey, mu1, sg1);
    float3 g2 = gauss3(ex, ey, mu2, sg2);
    g0b[p] = make_float4(sb, g0.x, g0.y, g0.z);
    g1b[p] = make_float4(sb, g1.x, g1.y, g1.z);
    g2b[p] = make_float4(sb, g2.x, g2.y, g2.z);
}

// ---------------- pad x [N,22] -> xp [N,32] ----------------
__global__ __launch_bounds__(256) void pad_x(const float* __restrict__ x,
                                             float* __restrict__ xp, int n) {
    int t = blockIdx.x * 256 + threadIdx.x;
    if (t >= n * 32) return;
    int r = t >> 5, c = t & 31;
    xp[t] = (c < 22) ? x[r * 22 + c] : 0.0f;
}

static __device__ __forceinline__ unsigned short bf16rne(float x) {
    unsigned u = __float_as_uint(x);
    u += 0x7FFFu + ((u >> 16) & 1u);      // round-to-nearest-even
    return (unsigned short)(u >> 16);
}

// ---- build transposed bf16 weights: Wcb[n][k], k-major contiguous (B-frag = 16 B) ----
// k in [0,3*CINP): segment g_k; k in [3*CINP,4*CINP): root. Zero-padded c>=CIN.
template <int CIN, int CINP, int COUTR>
__global__ __launch_bounds__(256) void build_wcb(const float* __restrict__ g,
                                                 const float* __restrict__ root,
                                                 unsigned short* __restrict__ Wcb) {
    constexpr int KT = 4 * CINP;
    int t = blockIdx.x * 256 + threadIdx.x;
    if (t >= COUTR * KT) return;
    int n = t / KT, k = t - n * KT;
    int seg = k / CINP, c = k - seg * CINP;
    float v = 0.0f;
    if (c < CIN)
        v = (seg < 3) ? g[c * (3 * COUTR) + seg * COUTR + n] : root[c * COUTR + n];
    Wcb[t] = bf16rne(v);
}

static __device__ __forceinline__ void fma4(float4& a, float g, const float4& hv) {
    a.x = fmaf(g, hv.x, a.x);
    a.y = fmaf(g, hv.y, a.y);
    a.z = fmaf(g, hv.z, a.z);
    a.w = fmaf(g, hv.w, a.w);
}

// ============ FUSED layer: aggregate -> bf16 LDS tile [S0|S1|S2|h] -> MFMA GEMM ============
// Block = 64 nodes. Phase 1: LPN=CINP/4 lanes/node; per edge: 1 record {src,g0,g1,g2} +
// 1 float4 h-gather + 12 FMA (exp hoisted to scatter_g). Own-row h folded in as 4th
// segment -> no restage/root VALU loop. Tile: 64 rows x KT bf16, odd float4 stride
// (17/33) -> conflict-free b128; 17.4 KB (CINP=32, 8 blk/CU) / 33.8 KB (CINP=64, 4 blk/CU).
// Phase 2: v_mfma_f32_16x16x32_bf16. Wave = 16-row strip; A-frag A[m=lane&15][k=quad*8+j]
// = one b128 LDS read; B-frag B[k=quad*8+j][n=lane&15] from transposed Wcb (L1-resident);
// C/D col=lane&15, row=quad*4+reg (HW-verified layouts). NOTE: out must NOT alias h.
template <int CINP, int COUTR>
__global__ __launch_bounds__(256) void fused_mfma(const float* __restrict__ h, int hs,
                                                  const float4* __restrict__ ged,
                                                  const int* __restrict__ cursor,
                                                  const int* __restrict__ degi,
                                                  const unsigned short* __restrict__ Wcb,
                                                  const float* __restrict__ bias,
                                                  float* __restrict__ out, int n) {
    constexpr int KT   = 4 * CINP;
    constexpr int ST4  = KT / 8 + 1;             // float4 per LDS row (odd)
    constexpr int ROWU = ST4 * 8;                // ushorts per LDS row
    constexpr int NSTEP = KT / 32;
    constexpr int NCT   = COUTR / 16;
    __shared__ float4 sa[64 * ST4];
    unsigned short* st = (unsigned short*)sa;
    const int row0 = blockIdx.x * 64;

    // ---------------- phase 1: aggregate + own-h into bf16 LDS tile ----------------
    {
        constexpr int LPN = CINP / 4;            // lanes per node (8 or 16)
        constexpr int NPP = 256 / LPN;           // nodes per pass (32 or 16)
        const int sub = threadIdx.x / LPN;
        const int li  = threadIdx.x % LPN;
#pragma unroll
        for (int pass = 0; pass < 64 / NPP; ++pass) {
            int lr = pass * NPP + sub;
            int node = row0 + lr; if (node > n - 1) node = n - 1;
            int end = cursor[node];
            int dg  = degi[node];
            int p   = end - dg;
            float4 a0 = {0, 0, 0, 0}, a1 = {0, 0, 0, 0}, a2 = {0, 0, 0, 0};
            for (; p + 4 <= end; p += 4) {
                float4 ed[4], hv[4];
#pragma unroll
                for (int u = 0; u < 4; ++u) ed[u] = ged[p + u];
#pragma unroll
                for (int u = 0; u < 4; ++u)
                    hv[u] = ((const float4*)(h + (long)__float_as_int(ed[u].x) * hs))[li];
#pragma unroll
                for (int u = 0; u < 4; ++u) {
                    fma4(a0, ed[u].y, hv[u]);
                    fma4(a1, ed[u].z, hv[u]);
                    fma4(a2, ed[u].w, hv[u]);
                }
            }
            for (; p < end; ++p) {
                float4 ed = ged[p];
                float4 hv = ((const float4*)(h + (long)__float_as_int(ed.x) * hs))[li];
                fma4(a0, ed.y, hv);
                fma4(a1, ed.z, hv);
                fma4(a2, ed.w, hv);
            }
            float inv = 1.0f / (float)max(dg, 1);
            fma4(a0, inv - 1.0f, a0);   // a *= inv
            fma4(a1, inv - 1.0f, a1);
            fma4(a2, inv - 1.0f, a2);
            float4 hv4 = ((const float4*)(h + (long)node * hs))[li];
            int base = lr * ROWU;
            int c4b  = li * 4;
            float4 aa[4] = {a0, a1, a2, hv4};
#pragma unroll
            for (int k = 0; k < 4; ++k) {
                ushort4 v;
                v.x = bf16rne(aa[k].x); v.y = bf16rne(aa[k].y);
                v.z = bf16rne(aa[k].z); v.w = bf16rne(aa[k].w);
                *(ushort4*)(st + base + k * CINP + c4b) = v;
            }
        }
    }
    __syncthreads();

    // ---------------- phase 2: MFMA GEMM from LDS tile ----------------
    const int lane = threadIdx.x & 63;
    const int wv   = threadIdx.x >> 6;           // wave -> rows [wv*16, wv*16+16)
    const int quad = lane >> 4;
    const int c16  = lane & 15;
    f32x4 acc[NCT];
#pragma unroll
    for (int ct = 0; ct < NCT; ++ct) acc[ct] = (f32x4){0.0f, 0.0f, 0.0f, 0.0f};
    const unsigned short* arow = st + (16 * wv + c16) * ROWU;
#pragma unroll
    for (int s = 0; s < NSTEP; ++s) {
        short8 af = *(const short8*)(arow + s * 32 + quad * 8);
#pragma unroll
        for (int ct = 0; ct < NCT; ++ct) {
            short8 bf = *(const short8*)(Wcb + (ct * 16 + c16) * KT + s * 32 + quad * 8);
            acc[ct] = __builtin_amdgcn_mfma_f32_16x16x32_bf16(af, bf, acc[ct], 0, 0, 0);
        }
    }
    // epilogue: C/D col=lane&15, row=quad*4+reg
#pragma unroll
    for (int ct = 0; ct < NCT; ++ct) {
        int col = ct * 16 + c16;
        float b = bias[col];
#pragma unroll
        for (int r = 0; r < 4; ++r) {
            int grow = row0 + wv * 16 + quad * 4 + r;
            if (grow < n)
                out[(long)grow * COUTR + col] = fmaxf(acc[ct][r] + b, 0.0f);
        }
    }
}

// ---------------- final FC (64->2) + log_softmax ----------------
__global__ __launch_bounds__(256) void final_kernel(const float* __restrict__ h,
                                                    const float* __restrict__ fcw,
                                                    const float* __restrict__ fcb,
                                                    float* __restrict__ out, int n) {
    int i = blockIdx.x * 256 + threadIdx.x;
    if (i >= n) return;
    const float4* h4 = (const float4*)(h + (long)i * 64);
    float l0 = fcb[0];
    float l1 = fcb[1];
#pragma unroll
    for (int j4 = 0; j4 < 16; ++j4) {
        float4 hv = h4[j4];
        l0 = fmaf(hv.x, fcw[8 * j4 + 0], l0);
        l1 = fmaf(hv.x, fcw[8 * j4 + 1], l1);
        l0 = fmaf(hv.y, fcw[8 * j4 + 2], l0);
        l1 = fmaf(hv.y, fcw[8 * j4 + 3], l1);
        l0 = fmaf(hv.z, fcw[8 * j4 + 4], l0);
        l1 = fmaf(hv.z, fcw[8 * j4 + 5], l1);
        l0 = fmaf(hv.w, fcw[8 * j4 + 6], l0);
        l1 = fmaf(hv.w, fcw[8 * j4 + 7], l1);
    }
    float mx  = fmaxf(l0, l1);
    float lse = mx + logf(__expf(l0 - mx) + __expf(l1 - mx));
    out[2 * (long)i]     = l0 - lse;
    out[2 * (long)i + 1] = l1 - lse;
}

extern "C" void kernel_launch(void* const* d_in, const int* in_sizes, int n_in,
                              void* d_out, int out_size, void* d_ws, size_t ws_size,
                              hipStream_t stream) {
    const float* x   = (const float*)d_in[0];
    const int*   ei  = (const int*)d_in[1];
    const float* ea  = (const float*)d_in[2];
    const float* g_[3]  = {(const float*)d_in[3],  (const float*)d_in[8],  (const float*)d_in[13]};
    const float* mu_[3] = {(const float*)d_in[4],  (const float*)d_in[9],  (const float*)d_in[14]};
    const float* sg_[3] = {(const float*)d_in[5],  (const float*)d_in[10], (const float*)d_in[15]};
    const float* rt_[3] = {(const float*)d_in[6],  (const float*)d_in[11], (const float*)d_in[16]};
    const float* bs_[3] = {(const float*)d_in[7],  (const float*)d_in[12], (const float*)d_in[17]};
    const float* fcw = (const float*)d_in[18];
    const float* fcb = (const float*)d_in[19];
    float* out = (float*)d_out;
    (void)in_sizes; (void)n_in; (void)out_size; (void)ws_size;

    // workspace carve-up (~85 MB)
    char* w = (char*)d_ws;
    size_t off = 0;
    auto carve = [&](size_t bytes) -> void* {
        void* p = (void*)(w + off);
        off += (bytes + 255) & ~(size_t)255;
        return p;
    };
    int*    degi   = (int*)carve((size_t)NN * 4);
    int*    cursor = (int*)carve((size_t)NN * 4);
    float4* ged0   = (float4*)carve((size_t)NE * 16);
    float4* ged1   = (float4*)carve((size_t)NE * 16);
    float4* ged2   = (float4*)carve((size_t)NE * 16);
    int*    bsum   = (int*)carve(1024 * 4);
    unsigned short* Wcb = (unsigned short*)carve((size_t)64 * 256 * 2);
    float*  xp     = (float*)carve((size_t)NN * 32 * 4);    // padded input [N,32]
    float*  hA     = (float*)carve((size_t)NN * 32 * 4);    // layer-0 out [N,32]
    float*  hB     = (float*)carve((size_t)NN * 64 * 4);    // layer-1 out [N,64]
    // xp/hA are adjacent 256-aligned carves forming a contiguous [N,64] region,
    // dead after layer 1 -> reuse as layer-2 out.
    float*  hC     = xp;

    const int* src = ei;
    const int* dst = ei + NE;
    const int EB = (NE + 255) / 256;
    const int GB = (NN + 63) / 64;   // 2561 blocks: 64 nodes per block

    // ---- CSR build + all-layer gaussians (once per call) ----
    hipMemsetAsync(degi, 0, (size_t)NN * 4, stream);
    deg_count<<<EB, 256, 0, stream>>>(dst, degi, NE);
    scan1<<<NB, 256, 0, stream>>>(degi, cursor, bsum, NN);
    scan2<<<1, 1024, 0, stream>>>(bsum, NB);
    scan3<<<NB, 256, 0, stream>>>(cursor, bsum, NN);
    scatter_g<<<EB, 256, 0, stream>>>(src, dst, ea, cursor,
                                      mu_[0], sg_[0], mu_[1], sg_[1], mu_[2], sg_[2],
                                      ged0, ged1, ged2, NE);
    pad_x<<<(NN * 32 + 255) / 256, 256, 0, stream>>>(x, xp, NN);

    // ---- layer 0: 22(pad32) -> 32 ----
    build_wcb<22, 32, 32><<<(32 * 128 + 255) / 256, 256, 0, stream>>>(g_[0], rt_[0], Wcb);
    fused_mfma<32, 32><<<GB, 256, 0, stream>>>(xp, 32, ged0, cursor, degi, Wcb, bs_[0], hA, NN);

    // ---- layer 1: 32 -> 64 ----
    build_wcb<32, 32, 64><<<(64 * 128 + 255) / 256, 256, 0, stream>>>(g_[1], rt_[1], Wcb);
    fused_mfma<32, 64><<<GB, 256, 0, stream>>>(hA, 32, ged1, cursor, degi, Wcb, bs_[1], hB, NN);

    // ---- layer 2: 64 -> 64 (out hC != h hB) ----
    build_wcb<64, 64, 64><<<(64 * 256 + 255) / 256, 256, 0, stream>>>(g_[2], rt_[2], Wcb);
    fused_mfma<64, 64><<<GB, 256, 0, stream>>>(hB, 64, ged2, cursor, degi, Wcb, bs_[2], hC, NN);

    final_kernel<<<(NN + 255) / 256, 256, 0, stream>>>(hC, fcw, fcb, out, NN);
}

// Round 18
// 419.039 us; speedup vs baseline: 1.3828x; 1.0130x over previous
//
#include <hip/hip_runtime.h>

#define NN 163842
#define NE 983040
#define NB 641   // ceil(NN/256)

using short8 = __attribute__((ext_vector_type(8))) short;
using f32x4  = __attribute__((ext_vector_type(4))) float;

// ---------------- degree count (int) ----------------
__global__ __launch_bounds__(256) void deg_count(const int* __restrict__ dst,
                                                 int* __restrict__ degi, int E) {
    int e = blockIdx.x * 256 + threadIdx.x;
    if (e < E) atomicAdd(&degi[dst[e]], 1);
}

// ---------------- exclusive scan of degi -> cursor ----------------
__global__ __launch_bounds__(256) void scan1(const int* __restrict__ degi,
                                             int* __restrict__ cursor,
                                             int* __restrict__ bsum, int n) {
    __shared__ int tmp[256];
    int t = threadIdx.x;
    int i = blockIdx.x * 256 + t;
    int v = (i < n) ? degi[i] : 0;
    tmp[t] = v;
    __syncthreads();
    for (int o = 1; o < 256; o <<= 1) {
        int x = (t >= o) ? tmp[t - o] : 0;
        __syncthreads();
        tmp[t] += x;
        __syncthreads();
    }
    if (i < n) cursor[i] = tmp[t] - v;            // exclusive
    if (t == 255) bsum[blockIdx.x] = tmp[255];    // block total
}

__global__ void scan2(int* __restrict__ bsum, int nb) {
    __shared__ int tmp[1024];
    int t = threadIdx.x;
    int v = (t < nb) ? bsum[t] : 0;
    tmp[t] = v;
    __syncthreads();
    for (int o = 1; o < 1024; o <<= 1) {
        int x = (t >= o) ? tmp[t - o] : 0;
        __syncthreads();
        tmp[t] += x;
        __syncthreads();
    }
    if (t < nb) bsum[t] = tmp[t] - v;
}

__global__ __launch_bounds__(256) void scan3(int* __restrict__ cursor,
                                             const int* __restrict__ bsum, int n) {
    int i = blockIdx.x * 256 + threadIdx.x;
    if (i < n) cursor[i] += bsum[blockIdx.x];
}

static __device__ __forceinline__ float3 gauss3(float ex, float ey,
                                                const float* __restrict__ mu,
                                                const float* __restrict__ sg) {
    float3 r;
    float dx, dy;
    dx = ex - mu[0]; dy = ey - mu[1];
    r.x = __expf(-0.5f * (dx * dx / (1e-15f + sg[0] * sg[0]) + dy * dy / (1e-15f + sg[1] * sg[1])));
    dx = ex - mu[2]; dy = ey - mu[3];
    r.y = __expf(-0.5f * (dx * dx / (1e-15f + sg[2] * sg[2]) + dy * dy / (1e-15f + sg[3] * sg[3])));
    dx = ex - mu[4]; dy = ey - mu[5];
    r.z = __expf(-0.5f * (dx * dx / (1e-15f + sg[4] * sg[4]) + dy * dy / (1e-15f + sg[5] * sg[5])));
    return r;
}

// ---- scatter + ALL per-layer gaussians: ged[l][p] = {src_bits, g0, g1, g2} ----
__global__ __launch_bounds__(256) void scatter_g(const int* __restrict__ src,
                                                 const int* __restrict__ dst,
                                                 const float* __restrict__ ea,
                                                 int* __restrict__ cursor,
                                                 const float* __restrict__ mu0, const float* __restrict__ sg0,
                                                 const float* __restrict__ mu1, const float* __restrict__ sg1,
                                                 const float* __restrict__ mu2, const float* __restrict__ sg2,
                                                 float4* __restrict__ g0b,
                                                 float4* __restrict__ g1b,
                                                 float4* __restrict__ g2b, int E) {
    int e = blockIdx.x * 256 + threadIdx.x;
    if (e >= E) return;
    int p = atomicAdd(&cursor[dst[e]], 1);
    float ex = ea[2 * e], ey = ea[2 * e + 1];
    float sb = __int_as_float(src[e]);
    float3 g0 = gauss3(ex, ey, mu0, sg0);
    float3 g1 = gauss3(ex, ey, mu1, sg1);
    float3 g2 = gauss3(ex, ey, mu2, sg2);
    g0b[p] = make_float4(sb, g0.x, g0.y, g0.z);
    g1b[p] = make_float4(sb, g1.x, g1.y, g1.z);
    g2b[p] = make_float4(sb, g2.x, g2.y, g2.z);
}

static __device__ __forceinline__ unsigned short bf16rne(float x) {
    unsigned u = __float_as_uint(x);
    u += 0x7FFFu + ((u >> 16) & 1u);      // round-to-nearest-even
    return (unsigned short)(u >> 16);
}

static __device__ __forceinline__ float bf2f(unsigned short u) {
    return __uint_as_float(((unsigned)u) << 16);
}

// ---------------- pad x [N,22] fp32 -> xp [N,32] bf16 ----------------
__global__ __launch_bounds__(256) void pad_x_bf(const float* __restrict__ x,
                                                unsigned short* __restrict__ xp, int n) {
    int t = blockIdx.x * 256 + threadIdx.x;
    if (t >= n * 32) return;
    int r = t >> 5, c = t & 31;
    xp[t] = bf16rne((c < 22) ? x[r * 22 + c] : 0.0f);
}

// ---- build transposed bf16 weights: Wcb[n][k], k-major contiguous (B-frag = 16 B) ----
template <int CIN, int CINP, int COUTR>
__global__ __launch_bounds__(256) void build_wcb(const float* __restrict__ g,
                                                 const float* __restrict__ root,
                                                 unsigned short* __restrict__ Wcb) {
    constexpr int KT = 4 * CINP;
    int t = blockIdx.x * 256 + threadIdx.x;
    if (t >= COUTR * KT) return;
    int n = t / KT, k = t - n * KT;
    int seg = k / CINP, c = k - seg * CINP;
    float v = 0.0f;
    if (c < CIN)
        v = (seg < 3) ? g[c * (3 * COUTR) + seg * COUTR + n] : root[c * COUTR + n];
    Wcb[t] = bf16rne(v);
}

static __device__ __forceinline__ void fma4(float4& a, float g, const float4& hv) {
    a.x = fmaf(g, hv.x, a.x);
    a.y = fmaf(g, hv.y, a.y);
    a.z = fmaf(g, hv.z, a.z);
    a.w = fmaf(g, hv.w, a.w);
}

static __device__ __forceinline__ float4 cvt4(ushort4 u) {
    return make_float4(bf2f(u.x), bf2f(u.y), bf2f(u.z), bf2f(u.w));
}

// ============ FUSED layer: aggregate (bf16 gather) -> bf16 LDS tile -> MFMA GEMM ============
// Block = 64 nodes. h stored bf16: gather = 8 B/lane (halves bytes; layer-2 working set
// 21 MB -> fits aggregate L2, cutting gather latency — round 17 was pure gather-latency
// at 15% VALU / 2% MFMA / 22% HBM). Phase 1: per edge 1 record {src,g0,g1,g2} + 1
// ushort4 gather + 4 cvt + 12 FMA. Own-row h copied into tile raw (already bf16).
// Tile: 64 x KT bf16, odd float4 stride -> 17.4/33.8 KB. Phase 2: mfma_f32_16x16x32_bf16,
// A-frag = b128 LDS read, B from transposed Wcb (L1-resident), C/D col=lane&15,
// row=quad*4+reg (HW-verified). Epilogue writes bf16. NOTE: out must NOT alias h.
template <int CINP, int COUTR>
__global__ __launch_bounds__(256) void fused_mfma(const unsigned short* __restrict__ h, int hs,
                                                  const float4* __restrict__ ged,
                                                  const int* __restrict__ cursor,
                                                  const int* __restrict__ degi,
                                                  const unsigned short* __restrict__ Wcb,
                                                  const float* __restrict__ bias,
                                                  unsigned short* __restrict__ out, int n) {
    constexpr int KT   = 4 * CINP;
    constexpr int ST4  = KT / 8 + 1;             // float4 per LDS row (odd)
    constexpr int ROWU = ST4 * 8;                // ushorts per LDS row
    constexpr int NSTEP = KT / 32;
    constexpr int NCT   = COUTR / 16;
    __shared__ float4 sa[64 * ST4];
    unsigned short* st = (unsigned short*)sa;
    const int row0 = blockIdx.x * 64;

    // ---------------- phase 1: aggregate + own-h into bf16 LDS tile ----------------
    {
        constexpr int LPN = CINP / 4;            // lanes per node (8 or 16)
        constexpr int NPP = 256 / LPN;           // nodes per pass (32 or 16)
        const int sub = threadIdx.x / LPN;
        const int li  = threadIdx.x % LPN;
#pragma unroll
        for (int pass = 0; pass < 64 / NPP; ++pass) {
            int lr = pass * NPP + sub;
            int node = row0 + lr; if (node > n - 1) node = n - 1;
            int end = cursor[node];
            int dg  = degi[node];
            int p   = end - dg;
            float4 a0 = {0, 0, 0, 0}, a1 = {0, 0, 0, 0}, a2 = {0, 0, 0, 0};
            for (; p + 4 <= end; p += 4) {
                float4 ed[4];
                ushort4 hu[4];
#pragma unroll
                for (int u = 0; u < 4; ++u) ed[u] = ged[p + u];
#pragma unroll
                for (int u = 0; u < 4; ++u)
                    hu[u] = *(const ushort4*)(h + (long)__float_as_int(ed[u].x) * hs + li * 4);
#pragma unroll
                for (int u = 0; u < 4; ++u) {
                    float4 hv = cvt4(hu[u]);
                    fma4(a0, ed[u].y, hv);
                    fma4(a1, ed[u].z, hv);
                    fma4(a2, ed[u].w, hv);
                }
            }
            for (; p < end; ++p) {
                float4 ed = ged[p];
                ushort4 hu = *(const ushort4*)(h + (long)__float_as_int(ed.x) * hs + li * 4);
                float4 hv = cvt4(hu);
                fma4(a0, ed.y, hv);
                fma4(a1, ed.z, hv);
                fma4(a2, ed.w, hv);
            }
            float inv = 1.0f / (float)max(dg, 1);
            fma4(a0, inv - 1.0f, a0);   // a *= inv
            fma4(a1, inv - 1.0f, a1);
            fma4(a2, inv - 1.0f, a2);
            ushort4 hv4 = *(const ushort4*)(h + (long)node * hs + li * 4);  // raw bf16 copy
            int base = lr * ROWU;
            int c4b  = li * 4;
            float4 aa[3] = {a0, a1, a2};
#pragma unroll
            for (int k = 0; k < 3; ++k) {
                ushort4 v;
                v.x = bf16rne(aa[k].x); v.y = bf16rne(aa[k].y);
                v.z = bf16rne(aa[k].z); v.w = bf16rne(aa[k].w);
                *(ushort4*)(st + base + k * CINP + c4b) = v;
            }
            *(ushort4*)(st + base + 3 * CINP + c4b) = hv4;
        }
    }
    __syncthreads();

    // ---------------- phase 2: MFMA GEMM from LDS tile ----------------
    const int lane = threadIdx.x & 63;
    const int wv   = threadIdx.x >> 6;           // wave -> rows [wv*16, wv*16+16)
    const int quad = lane >> 4;
    const int c16  = lane & 15;
    f32x4 acc[NCT];
#pragma unroll
    for (int ct = 0; ct < NCT; ++ct) acc[ct] = (f32x4){0.0f, 0.0f, 0.0f, 0.0f};
    const unsigned short* arow = st + (16 * wv + c16) * ROWU;
#pragma unroll
    for (int s = 0; s < NSTEP; ++s) {
        short8 af = *(const short8*)(arow + s * 32 + quad * 8);
#pragma unroll
        for (int ct = 0; ct < NCT; ++ct) {
            short8 bf = *(const short8*)(Wcb + (ct * 16 + c16) * KT + s * 32 + quad * 8);
            acc[ct] = __builtin_amdgcn_mfma_f32_16x16x32_bf16(af, bf, acc[ct], 0, 0, 0);
        }
    }
    // epilogue: C/D col=lane&15, row=quad*4+reg; write bf16
#pragma unroll
    for (int ct = 0; ct < NCT; ++ct) {
        int col = ct * 16 + c16;
        float b = bias[col];
#pragma unroll
        for (int r = 0; r < 4; ++r) {
            int grow = row0 + wv * 16 + quad * 4 + r;
            if (grow < n)
                out[(long)grow * COUTR + col] = bf16rne(fmaxf(acc[ct][r] + b, 0.0f));
        }
    }
}

// ---------------- final FC (64->2) + log_softmax (bf16 input) ----------------
__global__ __launch_bounds__(256) void final_kernel(const unsigned short* __restrict__ h,
                                                    const float* __restrict__ fcw,
                                                    const float* __restrict__ fcb,
                                                    float* __restrict__ out, int n) {
    int i = blockIdx.x * 256 + threadIdx.x;
    if (i >= n) return;
    const ushort4* h4 = (const ushort4*)(h + (long)i * 64);
    float l0 = fcb[0];
    float l1 = fcb[1];
#pragma unroll
    for (int j4 = 0; j4 < 16; ++j4) {
        ushort4 hu = h4[j4];
        float hv[4] = {bf2f(hu.x), bf2f(hu.y), bf2f(hu.z), bf2f(hu.w)};
#pragma unroll
        for (int j = 0; j < 4; ++j) {
            l0 = fmaf(hv[j], fcw[2 * (4 * j4 + j)], l0);
            l1 = fmaf(hv[j], fcw[2 * (4 * j4 + j) + 1], l1);
        }
    }
    float mx  = fmaxf(l0, l1);
    float lse = mx + logf(__expf(l0 - mx) + __expf(l1 - mx));
    out[2 * (long)i]     = l0 - lse;
    out[2 * (long)i + 1] = l1 - lse;
}

extern "C" void kernel_launch(void* const* d_in, const int* in_sizes, int n_in,
                              void* d_out, int out_size, void* d_ws, size_t ws_size,
                              hipStream_t stream) {
    const float* x   = (const float*)d_in[0];
    const int*   ei  = (const int*)d_in[1];
    const float* ea  = (const float*)d_in[2];
    const float* g_[3]  = {(const float*)d_in[3],  (const float*)d_in[8],  (const float*)d_in[13]};
    const float* mu_[3] = {(const float*)d_in[4],  (const float*)d_in[9],  (const float*)d_in[14]};
    const float* sg_[3] = {(const float*)d_in[5],  (const float*)d_in[10], (const float*)d_in[15]};
    const float* rt_[3] = {(const float*)d_in[6],  (const float*)d_in[11], (const float*)d_in[16]};
    const float* bs_[3] = {(const float*)d_in[7],  (const float*)d_in[12], (const float*)d_in[17]};
    const float* fcw = (const float*)d_in[18];
    const float* fcb = (const float*)d_in[19];
    float* out = (float*)d_out;
    (void)in_sizes; (void)n_in; (void)out_size; (void)ws_size;

    // workspace carve-up (~75 MB)
    char* w = (char*)d_ws;
    size_t off = 0;
    auto carve = [&](size_t bytes) -> void* {
        void* p = (void*)(w + off);
        off += (bytes + 255) & ~(size_t)255;
        return p;
    };
    int*    degi   = (int*)carve((size_t)NN * 4);
    int*    cursor = (int*)carve((size_t)NN * 4);
    float4* ged0   = (float4*)carve((size_t)NE * 16);
    float4* ged1   = (float4*)carve((size_t)NE * 16);
    float4* ged2   = (float4*)carve((size_t)NE * 16);
    int*    bsum   = (int*)carve(1024 * 4);
    unsigned short* Wcb = (unsigned short*)carve((size_t)64 * 256 * 2);
    unsigned short* xp  = (unsigned short*)carve((size_t)NN * 32 * 2);  // bf16 [N,32]
    unsigned short* hA  = (unsigned short*)carve((size_t)NN * 32 * 2);  // bf16 [N,32]
    unsigned short* hB  = (unsigned short*)carve((size_t)NN * 64 * 2);  // bf16 [N,64]
    unsigned short* hC  = (unsigned short*)carve((size_t)NN * 64 * 2);  // bf16 [N,64]

    const int* src = ei;
    const int* dst = ei + NE;
    const int EB = (NE + 255) / 256;
    const int GB = (NN + 63) / 64;   // 2561 blocks: 64 nodes per block

    // ---- CSR build + all-layer gaussians (once per call) ----
    hipMemsetAsync(degi, 0, (size_t)NN * 4, stream);
    deg_count<<<EB, 256, 0, stream>>>(dst, degi, NE);
    scan1<<<NB, 256, 0, stream>>>(degi, cursor, bsum, NN);
    scan2<<<1, 1024, 0, stream>>>(bsum, NB);
    scan3<<<NB, 256, 0, stream>>>(cursor, bsum, NN);
    scatter_g<<<EB, 256, 0, stream>>>(src, dst, ea, cursor,
                                      mu_[0], sg_[0], mu_[1], sg_[1], mu_[2], sg_[2],
                                      ged0, ged1, ged2, NE);
    pad_x_bf<<<(NN * 32 + 255) / 256, 256, 0, stream>>>(x, xp, NN);

    // ---- layer 0: 22(pad32) -> 32 ----
    build_wcb<22, 32, 32><<<(32 * 128 + 255) / 256, 256, 0, stream>>>(g_[0], rt_[0], Wcb);
    fused_mfma<32, 32><<<GB, 256, 0, stream>>>(xp, 32, ged0, cursor, degi, Wcb, bs_[0], hA, NN);

    // ---- layer 1: 32 -> 64 ----
    build_wcb<32, 32, 64><<<(64 * 128 + 255) / 256, 256, 0, stream>>>(g_[1], rt_[1], Wcb);
    fused_mfma<32, 64><<<GB, 256, 0, stream>>>(hA, 32, ged1, cursor, degi, Wcb, bs_[1], hB, NN);

    // ---- layer 2: 64 -> 64 (out hC != h hB) ----
    build_wcb<64, 64, 64><<<(64 * 256 + 255) / 256, 256, 0, stream>>>(g_[2], rt_[2], Wcb);
    fused_mfma<64, 64><<<GB, 256, 0, stream>>>(hB, 64, ged2, cursor, degi, Wcb, bs_[2], hC, NN);

    final_kernel<<<(NN + 255) / 256, 256, 0, stream>>>(hC, fcw, fcb, out, NN);
}

// Round 19
// 395.208 us; speedup vs baseline: 1.4662x; 1.0603x over previous
//
#include <hip/hip_runtime.h>

#define NN 163842
#define NE 983040
#define NB 641   // ceil(NN/256)

using short8   = __attribute__((ext_vector_type(8))) short;
using ushort8v = __attribute__((ext_vector_type(8))) unsigned short;
using f32x4    = __attribute__((ext_vector_type(4))) float;

// ---------------- degree count (int) ----------------
__global__ __launch_bounds__(256) void deg_count(const int* __restrict__ dst,
                                                 int* __restrict__ degi, int E) {
    int e = blockIdx.x * 256 + threadIdx.x;
    if (e < E) atomicAdd(&degi[dst[e]], 1);
}

// ---------------- exclusive scan of degi -> cursor ----------------
__global__ __launch_bounds__(256) void scan1(const int* __restrict__ degi,
                                             int* __restrict__ cursor,
                                             int* __restrict__ bsum, int n) {
    __shared__ int tmp[256];
    int t = threadIdx.x;
    int i = blockIdx.x * 256 + t;
    int v = (i < n) ? degi[i] : 0;
    tmp[t] = v;
    __syncthreads();
    for (int o = 1; o < 256; o <<= 1) {
        int x = (t >= o) ? tmp[t - o] : 0;
        __syncthreads();
        tmp[t] += x;
        __syncthreads();
    }
    if (i < n) cursor[i] = tmp[t] - v;            // exclusive
    if (t == 255) bsum[blockIdx.x] = tmp[255];    // block total
}

__global__ void scan2(int* __restrict__ bsum, int nb) {
    __shared__ int tmp[1024];
    int t = threadIdx.x;
    int v = (t < nb) ? bsum[t] : 0;
    tmp[t] = v;
    __syncthreads();
    for (int o = 1; o < 1024; o <<= 1) {
        int x = (t >= o) ? tmp[t - o] : 0;
        __syncthreads();
        tmp[t] += x;
        __syncthreads();
    }
    if (t < nb) bsum[t] = tmp[t] - v;
}

__global__ __launch_bounds__(256) void scan3(int* __restrict__ cursor,
                                             const int* __restrict__ bsum, int n) {
    int i = blockIdx.x * 256 + threadIdx.x;
    if (i < n) cursor[i] += bsum[blockIdx.x];
}

static __device__ __forceinline__ float3 gauss3(float ex, float ey,
                                                const float* __restrict__ mu,
                                                const float* __restrict__ sg) {
    float3 r;
    float dx, dy;
    dx = ex - mu[0]; dy = ey - mu[1];
    r.x = __expf(-0.5f * (dx * dx / (1e-15f + sg[0] * sg[0]) + dy * dy / (1e-15f + sg[1] * sg[1])));
    dx = ex - mu[2]; dy = ey - mu[3];
    r.y = __expf(-0.5f * (dx * dx / (1e-15f + sg[2] * sg[2]) + dy * dy / (1e-15f + sg[3] * sg[3])));
    dx = ex - mu[4]; dy = ey - mu[5];
    r.z = __expf(-0.5f * (dx * dx / (1e-15f + sg[4] * sg[4]) + dy * dy / (1e-15f + sg[5] * sg[5])));
    return r;
}

// ---- scatter + ALL per-layer gaussians: ged[l][p] = {src_bits, g0, g1, g2} ----
__global__ __launch_bounds__(256) void scatter_g(const int* __restrict__ src,
                                                 const int* __restrict__ dst,
                                                 const float* __restrict__ ea,
                                                 int* __restrict__ cursor,
                                                 const float* __restrict__ mu0, const float* __restrict__ sg0,
                                                 const float* __restrict__ mu1, const float* __restrict__ sg1,
                                                 const float* __restrict__ mu2, const float* __restrict__ sg2,
                                                 float4* __restrict__ g0b,
                                                 float4* __restrict__ g1b,
                                                 float4* __restrict__ g2b, int E) {
    int e = blockIdx.x * 256 + threadIdx.x;
    if (e >= E) return;
    int p = atomicAdd(&cursor[dst[e]], 1);
    float ex = ea[2 * e], ey = ea[2 * e + 1];
    float sb = __int_as_float(src[e]);
    float3 g0 = gauss3(ex, ey, mu0, sg0);
    float3 g1 = gauss3(ex, ey, mu1, sg1);
    float3 g2 = gauss3(ex, ey, mu2, sg2);
    g0b[p] = make_float4(sb, g0.x, g0.y, g0.z);
    g1b[p] = make_float4(sb, g1.x, g1.y, g1.z);
    g2b[p] = make_float4(sb, g2.x, g2.y, g2.z);
}

static __device__ __forceinline__ unsigned short bf16rne(float x) {
    unsigned u = __float_as_uint(x);
    u += 0x7FFFu + ((u >> 16) & 1u);      // round-to-nearest-even
    return (unsigned short)(u >> 16);
}

static __device__ __forceinline__ float bf2f(unsigned short u) {
    return __uint_as_float(((unsigned)u) << 16);
}

// ---------------- pad x [N,22] fp32 -> xp [N,32] bf16 ----------------
__global__ __launch_bounds__(256) void pad_x_bf(const float* __restrict__ x,
                                                unsigned short* __restrict__ xp, int n) {
    int t = blockIdx.x * 256 + threadIdx.x;
    if (t >= n * 32) return;
    int r = t >> 5, c = t & 31;
    xp[t] = bf16rne((c < 22) ? x[r * 22 + c] : 0.0f);
}

// ---- build transposed bf16 weights: Wcb[n][k], k-major contiguous (B-frag = 16 B) ----
template <int CIN, int CINP, int COUTR>
__global__ __launch_bounds__(256) void build_wcb(const float* __restrict__ g,
                                                 const float* __restrict__ root,
                                                 unsigned short* __restrict__ Wcb) {
    constexpr int KT = 4 * CINP;
    int t = blockIdx.x * 256 + threadIdx.x;
    if (t >= COUTR * KT) return;
    int n = t / KT, k = t - n * KT;
    int seg = k / CINP, c = k - seg * CINP;
    float v = 0.0f;
    if (c < CIN)
        v = (seg < 3) ? g[c * (3 * COUTR) + seg * COUTR + n] : root[c * COUTR + n];
    Wcb[t] = bf16rne(v);
}

static __device__ __forceinline__ void fma4(float4& a, float g, const float4& hv) {
    a.x = fmaf(g, hv.x, a.x);
    a.y = fmaf(g, hv.y, a.y);
    a.z = fmaf(g, hv.z, a.z);
    a.w = fmaf(g, hv.w, a.w);
}

// ============ FUSED layer: aggregate (16-B bf16 gather) -> bf16 LDS tile -> MFMA ============
// Block = 64 nodes. LPN = CINP/8 lanes per node (each lane gathers ushort8 = 16 B):
// 8 node-streams per wave at layer 2 (vs 4 in round 18) — round 18 was gather-LATENCY
// bound (HBM 12%, VALU 19%, MFMA 2%): double the independent dependent-chains and
// halve the load instructions. Phase 1 per edge: 1 record {src,g0,g1,g2} + 1 ushort8
// gather + 8 cvt + 24 FMA. acc = 6 float4/lane (~75 VGPR total — layer-2 occupancy is
// LDS-bound at 4 blk/CU so the extra regs are free; spill tripwire = WRITE_SIZE).
// Tile 64 x KT bf16, odd float4 stride (17/33) conflict-free. Phase 2:
// mfma_f32_16x16x32_bf16, A-frag b128 LDS read, B transposed Wcb (L1-resident),
// C/D col=lane&15, row=quad*4+reg (HW-verified). NOTE: out must NOT alias h.
template <int CINP, int COUTR>
__global__ __launch_bounds__(256) void fused_mfma(const unsigned short* __restrict__ h, int hs,
                                                  const float4* __restrict__ ged,
                                                  const int* __restrict__ cursor,
                                                  const int* __restrict__ degi,
                                                  const unsigned short* __restrict__ Wcb,
                                                  const float* __restrict__ bias,
                                                  unsigned short* __restrict__ out, int n) {
    constexpr int KT   = 4 * CINP;
    constexpr int ST4  = KT / 8 + 1;             // float4 per LDS row (odd)
    constexpr int ROWU = ST4 * 8;                // ushorts per LDS row
    constexpr int NSTEP = KT / 32;
    constexpr int NCT   = COUTR / 16;
    __shared__ float4 sa[64 * ST4];
    unsigned short* st = (unsigned short*)sa;
    const int row0 = blockIdx.x * 64;

    // ---------------- phase 1: aggregate + own-h into bf16 LDS tile ----------------
    {
        constexpr int LPN = CINP / 8;            // lanes per node (4 or 8)
        constexpr int NPP = 256 / LPN;           // nodes per pass (64 or 32)
        const int sub = threadIdx.x / LPN;
        const int li  = threadIdx.x % LPN;       // covers bf16 [li*8, li*8+8)
#pragma unroll
        for (int pass = 0; pass < 64 / NPP; ++pass) {
            int lr = pass * NPP + sub;
            int node = row0 + lr; if (node > n - 1) node = n - 1;
            int end = cursor[node];
            int dg  = degi[node];
            int p   = end - dg;
            float4 a[3][2];
#pragma unroll
            for (int k = 0; k < 3; ++k)
#pragma unroll
                for (int q = 0; q < 2; ++q) a[k][q] = make_float4(0, 0, 0, 0);
            for (; p + 4 <= end; p += 4) {
                float4 ed[4];
                ushort8v hu[4];
#pragma unroll
                for (int u = 0; u < 4; ++u) ed[u] = ged[p + u];
#pragma unroll
                for (int u = 0; u < 4; ++u)
                    hu[u] = *(const ushort8v*)(h + (long)__float_as_int(ed[u].x) * hs + li * 8);
#pragma unroll
                for (int u = 0; u < 4; ++u) {
                    float4 h0 = make_float4(bf2f(hu[u][0]), bf2f(hu[u][1]),
                                            bf2f(hu[u][2]), bf2f(hu[u][3]));
                    float4 h1 = make_float4(bf2f(hu[u][4]), bf2f(hu[u][5]),
                                            bf2f(hu[u][6]), bf2f(hu[u][7]));
                    fma4(a[0][0], ed[u].y, h0); fma4(a[0][1], ed[u].y, h1);
                    fma4(a[1][0], ed[u].z, h0); fma4(a[1][1], ed[u].z, h1);
                    fma4(a[2][0], ed[u].w, h0); fma4(a[2][1], ed[u].w, h1);
                }
            }
            for (; p < end; ++p) {
                float4 ed = ged[p];
                ushort8v hu = *(const ushort8v*)(h + (long)__float_as_int(ed.x) * hs + li * 8);
                float4 h0 = make_float4(bf2f(hu[0]), bf2f(hu[1]), bf2f(hu[2]), bf2f(hu[3]));
                float4 h1 = make_float4(bf2f(hu[4]), bf2f(hu[5]), bf2f(hu[6]), bf2f(hu[7]));
                fma4(a[0][0], ed.y, h0); fma4(a[0][1], ed.y, h1);
                fma4(a[1][0], ed.z, h0); fma4(a[1][1], ed.z, h1);
                fma4(a[2][0], ed.w, h0); fma4(a[2][1], ed.w, h1);
            }
            float inv = 1.0f / (float)max(dg, 1);
#pragma unroll
            for (int k = 0; k < 3; ++k)
#pragma unroll
                for (int q = 0; q < 2; ++q) fma4(a[k][q], inv - 1.0f, a[k][q]);  // *= inv
            ushort8v hv8 = *(const ushort8v*)(h + (long)node * hs + li * 8);  // raw bf16
            int base = lr * ROWU;
            int c8b  = li * 8;
#pragma unroll
            for (int k = 0; k < 3; ++k) {
                ushort8v v;
                v[0] = bf16rne(a[k][0].x); v[1] = bf16rne(a[k][0].y);
                v[2] = bf16rne(a[k][0].z); v[3] = bf16rne(a[k][0].w);
                v[4] = bf16rne(a[k][1].x); v[5] = bf16rne(a[k][1].y);
                v[6] = bf16rne(a[k][1].z); v[7] = bf16rne(a[k][1].w);
                *(ushort8v*)(st + base + k * CINP + c8b) = v;
            }
            *(ushort8v*)(st + base + 3 * CINP + c8b) = hv8;
        }
    }
    __syncthreads();

    // ---------------- phase 2: MFMA GEMM from LDS tile ----------------
    const int lane = threadIdx.x & 63;
    const int wv   = threadIdx.x >> 6;           // wave -> rows [wv*16, wv*16+16)
    const int quad = lane >> 4;
    const int c16  = lane & 15;
    f32x4 acc[NCT];
#pragma unroll
    for (int ct = 0; ct < NCT; ++ct) acc[ct] = (f32x4){0.0f, 0.0f, 0.0f, 0.0f};
    const unsigned short* arow = st + (16 * wv + c16) * ROWU;
#pragma unroll
    for (int s = 0; s < NSTEP; ++s) {
        short8 af = *(const short8*)(arow + s * 32 + quad * 8);
#pragma unroll
        for (int ct = 0; ct < NCT; ++ct) {
            short8 bf = *(const short8*)(Wcb + (ct * 16 + c16) * KT + s * 32 + quad * 8);
            acc[ct] = __builtin_amdgcn_mfma_f32_16x16x32_bf16(af, bf, acc[ct], 0, 0, 0);
        }
    }
    // epilogue: C/D col=lane&15, row=quad*4+reg; write bf16
#pragma unroll
    for (int ct = 0; ct < NCT; ++ct) {
        int col = ct * 16 + c16;
        float b = bias[col];
#pragma unroll
        for (int r = 0; r < 4; ++r) {
            int grow = row0 + wv * 16 + quad * 4 + r;
            if (grow < n)
                out[(long)grow * COUTR + col] = bf16rne(fmaxf(acc[ct][r] + b, 0.0f));
        }
    }
}

// ---------------- final FC (64->2) + log_softmax (bf16 input) ----------------
__global__ __launch_bounds__(256) void final_kernel(const unsigned short* __restrict__ h,
                                                    const float* __restrict__ fcw,
                                                    const float* __restrict__ fcb,
                                                    float* __restrict__ out, int n) {
    int i = blockIdx.x * 256 + threadIdx.x;
    if (i >= n) return;
    const ushort4* h4 = (const ushort4*)(h + (long)i * 64);
    float l0 = fcb[0];
    float l1 = fcb[1];
#pragma unroll
    for (int j4 = 0; j4 < 16; ++j4) {
        ushort4 hu = h4[j4];
        float hv[4] = {bf2f(hu.x), bf2f(hu.y), bf2f(hu.z), bf2f(hu.w)};
#pragma unroll
        for (int j = 0; j < 4; ++j) {
            l0 = fmaf(hv[j], fcw[2 * (4 * j4 + j)], l0);
            l1 = fmaf(hv[j], fcw[2 * (4 * j4 + j) + 1], l1);
        }
    }
    float mx  = fmaxf(l0, l1);
    float lse = mx + logf(__expf(l0 - mx) + __expf(l1 - mx));
    out[2 * (long)i]     = l0 - lse;
    out[2 * (long)i + 1] = l1 - lse;
}

extern "C" void kernel_launch(void* const* d_in, const int* in_sizes, int n_in,
                              void* d_out, int out_size, void* d_ws, size_t ws_size,
                              hipStream_t stream) {
    const float* x   = (const float*)d_in[0];
    const int*   ei  = (const int*)d_in[1];
    const float* ea  = (const float*)d_in[2];
    const float* g_[3]  = {(const float*)d_in[3],  (const float*)d_in[8],  (const float*)d_in[13]};
    const float* mu_[3] = {(const float*)d_in[4],  (const float*)d_in[9],  (const float*)d_in[14]};
    const float* sg_[3] = {(const float*)d_in[5],  (const float*)d_in[10], (const float*)d_in[15]};
    const float* rt_[3] = {(const float*)d_in[6],  (const float*)d_in[11], (const float*)d_in[16]};
    const float* bs_[3] = {(const float*)d_in[7],  (const float*)d_in[12], (const float*)d_in[17]};
    const float* fcw = (const float*)d_in[18];
    const float* fcb = (const float*)d_in[19];
    float* out = (float*)d_out;
    (void)in_sizes; (void)n_in; (void)out_size; (void)ws_size;

    // workspace carve-up (~75 MB)
    char* w = (char*)d_ws;
    size_t off = 0;
    auto carve = [&](size_t bytes) -> void* {
        void* p = (void*)(w + off);
        off += (bytes + 255) & ~(size_t)255;
        return p;
    };
    int*    degi   = (int*)carve((size_t)NN * 4);
    int*    cursor = (int*)carve((size_t)NN * 4);
    float4* ged0   = (float4*)carve((size_t)NE * 16);
    float4* ged1   = (float4*)carve((size_t)NE * 16);
    float4* ged2   = (float4*)carve((size_t)NE * 16);
    int*    bsum   = (int*)carve(1024 * 4);
    unsigned short* Wcb = (unsigned short*)carve((size_t)64 * 256 * 2);
    unsigned short* xp  = (unsigned short*)carve((size_t)NN * 32 * 2);  // bf16 [N,32]
    unsigned short* hA  = (unsigned short*)carve((size_t)NN * 32 * 2);  // bf16 [N,32]
    unsigned short* hB  = (unsigned short*)carve((size_t)NN * 64 * 2);  // bf16 [N,64]
    unsigned short* hC  = (unsigned short*)carve((size_t)NN * 64 * 2);  // bf16 [N,64]

    const int* src = ei;
    const int* dst = ei + NE;
    const int EB = (NE + 255) / 256;
    const int GB = (NN + 63) / 64;   // 2561 blocks: 64 nodes per block

    // ---- CSR build + all-layer gaussians (once per call) ----
    hipMemsetAsync(degi, 0, (size_t)NN * 4, stream);
    deg_count<<<EB, 256, 0, stream>>>(dst, degi, NE);
    scan1<<<NB, 256, 0, stream>>>(degi, cursor, bsum, NN);
    scan2<<<1, 1024, 0, stream>>>(bsum, NB);
    scan3<<<NB, 256, 0, stream>>>(cursor, bsum, NN);
    scatter_g<<<EB, 256, 0, stream>>>(src, dst, ea, cursor,
                                      mu_[0], sg_[0], mu_[1], sg_[1], mu_[2], sg_[2],
                                      ged0, ged1, ged2, NE);
    pad_x_bf<<<(NN * 32 + 255) / 256, 256, 0, stream>>>(x, xp, NN);

    // ---- layer 0: 22(pad32) -> 32 ----
    build_wcb<22, 32, 32><<<(32 * 128 + 255) / 256, 256, 0, stream>>>(g_[0], rt_[0], Wcb);
    fused_mfma<32, 32><<<GB, 256, 0, stream>>>(xp, 32, ged0, cursor, degi, Wcb, bs_[0], hA, NN);

    // ---- layer 1: 32 -> 64 ----
    build_wcb<32, 32, 64><<<(64 * 128 + 255) / 256, 256, 0, stream>>>(g_[1], rt_[1], Wcb);
    fused_mfma<32, 64><<<GB, 256, 0, stream>>>(hA, 32, ged1, cursor, degi, Wcb, bs_[1], hB, NN);

    // ---- layer 2: 64 -> 64 (out hC != h hB) ----
    build_wcb<64, 64, 64><<<(64 * 256 + 255) / 256, 256, 0, stream>>>(g_[2], rt_[2], Wcb);
    fused_mfma<64, 64><<<GB, 256, 0, stream>>>(hB, 64, ged2, cursor, degi, Wcb, bs_[2], hC, NN);

    final_kernel<<<(NN + 255) / 256, 256, 0, stream>>>(hC, fcw, fcb, out, NN);
}